// Round 1
// baseline (688.199 us; speedup 1.0000x reference)
//
#include <hip/hip_runtime.h>
#include <hip/hip_bf16.h>

#define NN   100000
#define C0   40000
#define C1   30000
#define C2   30000
#define HID  64
#define KK   8
#define EE   1600000
#define DIN  512
#define NCLS 16
#define NCH  98   // ceil(NN/1024)

// ---------------- pre GEMM: h[0:40000] = feats0 @ W_pre + b_pre ----------------
__global__ __launch_bounds__(256) void pre_gemm(const float* __restrict__ A,
                                                const float* __restrict__ W,
                                                const float* __restrict__ b,
                                                float* __restrict__ h) {
    __shared__ float As[64][65];   // padded: 2-way bank aliasing only (free)
    __shared__ float Bs[64][64];
    const int tid = threadIdx.x;
    const int row0 = blockIdx.x * 64;
    const int tx = tid & 15, ty = tid >> 4;
    float acc[4][4] = {};
    for (int k0 = 0; k0 < DIN; k0 += 64) {
        // load A tile (64 rows x 64 cols), float4 loads, scalar stores (pad)
        for (int i = tid; i < 64 * 16; i += 256) {
            int r = i >> 4, c4 = i & 15;
            float4 v = *(const float4*)(A + (size_t)(row0 + r) * DIN + k0 + c4 * 4);
            As[r][c4 * 4 + 0] = v.x; As[r][c4 * 4 + 1] = v.y;
            As[r][c4 * 4 + 2] = v.z; As[r][c4 * 4 + 3] = v.w;
        }
        // load B tile: W[k0+r][c], contiguous 16KB
        for (int i = tid; i < 64 * 16; i += 256) {
            int r = i >> 4, c4 = i & 15;
            *(float4*)(&Bs[r][c4 * 4]) = *(const float4*)(W + (size_t)(k0 + r) * HID + c4 * 4);
        }
        __syncthreads();
        for (int kk = 0; kk < 64; ++kk) {
            float a0 = As[ty * 4 + 0][kk], a1 = As[ty * 4 + 1][kk];
            float a2 = As[ty * 4 + 2][kk], a3 = As[ty * 4 + 3][kk];
            float4 bv = *(const float4*)(&Bs[kk][tx * 4]);
            acc[0][0] += a0 * bv.x; acc[0][1] += a0 * bv.y; acc[0][2] += a0 * bv.z; acc[0][3] += a0 * bv.w;
            acc[1][0] += a1 * bv.x; acc[1][1] += a1 * bv.y; acc[1][2] += a1 * bv.z; acc[1][3] += a1 * bv.w;
            acc[2][0] += a2 * bv.x; acc[2][1] += a2 * bv.y; acc[2][2] += a2 * bv.z; acc[2][3] += a2 * bv.w;
            acc[3][0] += a3 * bv.x; acc[3][1] += a3 * bv.y; acc[3][2] += a3 * bv.z; acc[3][3] += a3 * bv.w;
        }
        __syncthreads();
    }
    float4 bb = *(const float4*)(b + tx * 4);
    for (int r = 0; r < 4; ++r) {
        float4 o;
        o.x = acc[r][0] + bb.x; o.y = acc[r][1] + bb.y;
        o.z = acc[r][2] + bb.z; o.w = acc[r][3] + bb.w;
        *(float4*)(h + (size_t)(row0 + ty * 4 + r) * HID + tx * 4) = o;
    }
}

// ---------------- degree histogram ----------------
__global__ void count_deg(const int* __restrict__ dst, int* __restrict__ deg) {
    int i = blockIdx.x * blockDim.x + threadIdx.x;
    if (i < EE) atomicAdd(&deg[dst[i]], 1);
}

// ---------------- scan (3 kernels) ----------------
__global__ __launch_bounds__(256) void scan_partial(const int* __restrict__ deg,
                                                    int* __restrict__ partials) {
    __shared__ int sm[256];
    const int b = blockIdx.x, t = threadIdx.x;
    const int base = b * 1024 + t * 4;
    int s = 0;
    #pragma unroll
    for (int c = 0; c < 4; ++c) { int n = base + c; if (n < NN) s += deg[n]; }
    sm[t] = s;
    __syncthreads();
    for (int off = 128; off > 0; off >>= 1) {
        if (t < off) sm[t] += sm[t + off];
        __syncthreads();
    }
    if (t == 0) partials[b] = sm[0];
}

__global__ void scan_top(int* __restrict__ partials, int* __restrict__ offs) {
    if (threadIdx.x == 0 && blockIdx.x == 0) {
        int run = 0;
        for (int i = 0; i < NCH; ++i) { int v = partials[i]; partials[i] = run; run += v; }
        offs[NN] = EE;
    }
}

__global__ __launch_bounds__(256) void scan_final(const int* __restrict__ deg,
                                                  const int* __restrict__ partials,
                                                  int* __restrict__ offs,
                                                  int* __restrict__ cursor) {
    __shared__ int sm[256];
    const int b = blockIdx.x, t = threadIdx.x;
    const int base = b * 1024 + t * 4;
    int v[4];
    int s = 0;
    #pragma unroll
    for (int c = 0; c < 4; ++c) {
        v[c] = (base + c < NN) ? deg[base + c] : 0;
        s += v[c];
    }
    sm[t] = s;
    __syncthreads();
    for (int off = 1; off < 256; off <<= 1) {
        int y = (t >= off) ? sm[t - off] : 0;
        __syncthreads();
        sm[t] += y;
        __syncthreads();
    }
    int run = partials[b] + sm[t] - s;    // exclusive prefix
    #pragma unroll
    for (int c = 0; c < 4; ++c) {
        if (base + c < NN) { offs[base + c] = run; cursor[base + c] = run; }
        run += v[c];
    }
}

// ---------------- scatter edges into CSR ----------------
__global__ void scatter_edges(const int* __restrict__ src, const int* __restrict__ dst,
                              int* __restrict__ cursor, int* __restrict__ ssrc) {
    int i = blockIdx.x * blockDim.x + threadIdx.x;
    if (i < EE) {
        int p = atomicAdd(&cursor[dst[i]], 1);
        ssrc[p] = src[i];
    }
}

// ---------------- spmm (CSR gather), wave per node ----------------
__global__ __launch_bounds__(256) void spmm_csr(const float* __restrict__ h,
                                                const int* __restrict__ offs,
                                                const int* __restrict__ ssrc,
                                                float* __restrict__ agg,
                                                int filter_c0) {
    const int wv = threadIdx.x >> 6, lane = threadIdx.x & 63;
    const int n = blockIdx.x * 4 + wv;
    const int beg = offs[n], end = offs[n + 1];
    float acc = 0.f;
    if (filter_c0) {
        for (int j = beg; j < end; ++j) {
            int s = ssrc[j];
            if (s < C0) acc += h[(size_t)s * HID + lane];   // wave-uniform branch
        }
    } else {
        for (int j = beg; j < end; ++j) {
            int s = ssrc[j];
            acc += h[(size_t)s * HID + lane];
        }
    }
    float d = (float)(end - beg);
    agg[(size_t)n * HID + lane] = acc / fmaxf(d, 1.0f);
}

// ---------------- k-attention + segment FC (fused, in-place h0 -> h_t) ----------------
__global__ __launch_bounds__(256) void katt_fc(float* __restrict__ h,
                                               const float* __restrict__ agg,
                                               const int* __restrict__ node_assign,
                                               const float* __restrict__ op_W,
                                               const float* __restrict__ op_b,
                                               const float* __restrict__ emb_W,
                                               const float* __restrict__ emb_b,
                                               const float* __restrict__ fc_W,
                                               const float* __restrict__ fc_b) {
    __shared__ float rb[4][64];
    const int wv = threadIdx.x >> 6, lane = threadIdx.x & 63;
    const int n = blockIdx.x * 4 + wv;
    const int nb = blockIdx.x * 4;                       // block-uniform segment
    const int seg = (nb < C0) ? 0 : (nb < C0 + C1 ? 1 : 2);
    const int k = node_assign[n];
    float a = agg[(size_t)n * HID + lane];
    rb[wv][lane] = a;
    __syncthreads();
    const float* Wk = op_W + (size_t)k * HID * HID;
    float o = 0.f;
    #pragma unroll 8
    for (int j = 0; j < HID; ++j) o += rb[wv][j] * Wk[j * HID + lane];
    float hatt = h[(size_t)n * HID + lane] + o + op_b[k * HID + lane];
    if (seg == 1)
        hatt += emb_W[(size_t)(n - C0) * HID + lane] + emb_b[lane];
    else if (seg == 2)
        hatt += emb_W[(size_t)C1 * HID + (size_t)(n - C0 - C1) * HID + lane] + emb_b[HID + lane];
    float ht;
    if (seg == 0) {
        ht = hatt;
    } else {
        __syncthreads();
        rb[wv][lane] = hatt;
        __syncthreads();
        const float* Wf = fc_W + (size_t)(seg - 1) * HID * HID;
        float o2 = 0.f;
        #pragma unroll 8
        for (int j = 0; j < HID; ++j) o2 += rb[wv][j] * Wf[j * HID + lane];
        ht = o2 + fc_b[(seg - 1) * HID + lane];
    }
    h[(size_t)n * HID + lane] = ht;
}

// ---------------- final: gnn matvec + elu + logits ----------------
__global__ __launch_bounds__(256) void final_k(const float* __restrict__ agg,
                                               const float* __restrict__ gnn_W,
                                               const float* __restrict__ gnn_b,
                                               const float* __restrict__ out_W,
                                               const float* __restrict__ out_b,
                                               float* __restrict__ out) {
    __shared__ float rb[4][64];
    const int wv = threadIdx.x >> 6, lane = threadIdx.x & 63;
    const int n = blockIdx.x * 4 + wv;
    float a = agg[(size_t)n * HID + lane];
    rb[wv][lane] = a;
    __syncthreads();
    float o = 0.f;
    #pragma unroll 8
    for (int j = 0; j < HID; ++j) o += rb[wv][j] * gnn_W[j * HID + lane];
    o += gnn_b[lane];
    float emb = (o > 0.f) ? o : expm1f(o);   // elu, alpha=1
    out[(size_t)n * HID + lane] = emb;
    __syncthreads();
    rb[wv][lane] = emb;
    __syncthreads();
    if (lane < NCLS) {
        float lg = 0.f;
        #pragma unroll 8
        for (int j = 0; j < HID; ++j) lg += rb[wv][j] * out_W[j * NCLS + lane];
        lg += out_b[lane];
        const size_t lbase = (size_t)NN * HID;
        out[lbase + (size_t)n * NCLS + lane] = lg;
        out[lbase + (size_t)NN * NCLS + (size_t)n * NCLS + lane] = lg;
    }
}

extern "C" void kernel_launch(void* const* d_in, const int* in_sizes, int n_in,
                              void* d_out, int out_size, void* d_ws, size_t ws_size,
                              hipStream_t stream) {
    const float* feats0 = (const float*)d_in[0];
    const float* W_pre  = (const float*)d_in[1];
    const float* b_pre  = (const float*)d_in[2];
    const float* emb_W  = (const float*)d_in[3];
    const float* emb_b  = (const float*)d_in[4];
    const float* op_W   = (const float*)d_in[5];
    const float* op_b   = (const float*)d_in[6];
    const float* fc_W   = (const float*)d_in[7];
    const float* fc_b   = (const float*)d_in[8];
    const float* gnn_W  = (const float*)d_in[9];
    const float* gnn_b  = (const float*)d_in[10];
    const float* out_W  = (const float*)d_in[11];
    const float* out_b  = (const float*)d_in[12];
    const int* src         = (const int*)d_in[13];
    const int* dst         = (const int*)d_in[14];
    const int* node_assign = (const int*)d_in[15];
    float* out = (float*)d_out;

    // workspace layout (~58.9 MB)
    float* h    = (float*)d_ws;                       // NN*64 f32 (h0 -> h_t in place)
    float* agg  = h + (size_t)NN * HID;               // NN*64 f32
    int* deg    = (int*)(agg + (size_t)NN * HID);     // NN
    int* offs   = deg + NN;                           // NN+1
    int* cursor = offs + NN + 1;                      // NN
    int* ssrc   = cursor + NN;                        // EE
    int* partials = ssrc + EE;                        // NCH

    hipMemsetAsync(deg, 0, NN * sizeof(int), stream);
    hipMemsetAsync(h + (size_t)C0 * HID, 0, (size_t)(NN - C0) * HID * sizeof(float), stream);

    pre_gemm<<<C0 / 64, 256, 0, stream>>>(feats0, W_pre, b_pre, h);
    count_deg<<<(EE + 255) / 256, 256, 0, stream>>>(dst, deg);
    scan_partial<<<NCH, 256, 0, stream>>>(deg, partials);
    scan_top<<<1, 64, 0, stream>>>(partials, offs);
    scan_final<<<NCH, 256, 0, stream>>>(deg, partials, offs, cursor);
    scatter_edges<<<(EE + 255) / 256, 256, 0, stream>>>(src, dst, cursor, ssrc);
    spmm_csr<<<NN / 4, 256, 0, stream>>>(h, offs, ssrc, agg, 1);
    katt_fc<<<NN / 4, 256, 0, stream>>>(h, agg, node_assign, op_W, op_b, emb_W, emb_b, fc_W, fc_b);
    spmm_csr<<<NN / 4, 256, 0, stream>>>(h, offs, ssrc, agg, 0);
    final_k<<<NN / 4, 256, 0, stream>>>(agg, gnn_W, gnn_b, out_W, out_b, out);
}

// Round 2
// 511.301 us; speedup vs baseline: 1.3460x; 1.3460x over previous
//
#include <hip/hip_runtime.h>
#include <hip/hip_bf16.h>

#define NN   100000
#define C0   40000
#define C1   30000
#define C2   30000
#define HID  64
#define KK   8
#define EE   1600000
#define DIN  512
#define NCLS 16
#define NCH  98   // ceil(NN/1024)

// ---------------- pre GEMM: h[0:40000] = feats0 @ W_pre + b_pre ----------------
__global__ __launch_bounds__(256) void pre_gemm(const float* __restrict__ A,
                                                const float* __restrict__ W,
                                                const float* __restrict__ b,
                                                float* __restrict__ h) {
    __shared__ float As[64][65];
    __shared__ float Bs[64][64];
    const int tid = threadIdx.x;
    const int row0 = blockIdx.x * 64;
    const int tx = tid & 15, ty = tid >> 4;
    float acc[4][4] = {};
    for (int k0 = 0; k0 < DIN; k0 += 64) {
        for (int i = tid; i < 64 * 16; i += 256) {
            int r = i >> 4, c4 = i & 15;
            float4 v = *(const float4*)(A + (size_t)(row0 + r) * DIN + k0 + c4 * 4);
            As[r][c4 * 4 + 0] = v.x; As[r][c4 * 4 + 1] = v.y;
            As[r][c4 * 4 + 2] = v.z; As[r][c4 * 4 + 3] = v.w;
        }
        for (int i = tid; i < 64 * 16; i += 256) {
            int r = i >> 4, c4 = i & 15;
            *(float4*)(&Bs[r][c4 * 4]) = *(const float4*)(W + (size_t)(k0 + r) * HID + c4 * 4);
        }
        __syncthreads();
        for (int kk = 0; kk < 64; ++kk) {
            float a0 = As[ty * 4 + 0][kk], a1 = As[ty * 4 + 1][kk];
            float a2 = As[ty * 4 + 2][kk], a3 = As[ty * 4 + 3][kk];
            float4 bv = *(const float4*)(&Bs[kk][tx * 4]);
            acc[0][0] += a0 * bv.x; acc[0][1] += a0 * bv.y; acc[0][2] += a0 * bv.z; acc[0][3] += a0 * bv.w;
            acc[1][0] += a1 * bv.x; acc[1][1] += a1 * bv.y; acc[1][2] += a1 * bv.z; acc[1][3] += a1 * bv.w;
            acc[2][0] += a2 * bv.x; acc[2][1] += a2 * bv.y; acc[2][2] += a2 * bv.z; acc[2][3] += a2 * bv.w;
            acc[3][0] += a3 * bv.x; acc[3][1] += a3 * bv.y; acc[3][2] += a3 * bv.z; acc[3][3] += a3 * bv.w;
        }
        __syncthreads();
    }
    float4 bb = *(const float4*)(b + tx * 4);
    for (int r = 0; r < 4; ++r) {
        float4 o;
        o.x = acc[r][0] + bb.x; o.y = acc[r][1] + bb.y;
        o.z = acc[r][2] + bb.z; o.w = acc[r][3] + bb.w;
        *(float4*)(h + (size_t)(row0 + ty * 4 + r) * HID + tx * 4) = o;
    }
}

// ---------------- degree histograms (all edges + src<C0 edges) ----------------
__global__ void count_deg2(const int* __restrict__ src, const int* __restrict__ dst,
                           int* __restrict__ deg, int* __restrict__ deg1) {
    int i = (blockIdx.x * blockDim.x + threadIdx.x) * 2;
    int2 d = *(const int2*)(dst + i);
    int2 s = *(const int2*)(src + i);
    atomicAdd(&deg[d.x], 1);
    atomicAdd(&deg[d.y], 1);
    if (s.x < C0) atomicAdd(&deg1[d.x], 1);
    if (s.y < C0) atomicAdd(&deg1[d.y], 1);
}

// ---------------- scan (3 kernels) ----------------
__global__ __launch_bounds__(256) void scan_partial(const int* __restrict__ deg,
                                                    int* __restrict__ partials) {
    __shared__ int sm[256];
    const int b = blockIdx.x, t = threadIdx.x;
    const int base = b * 1024 + t * 4;
    int s = 0;
    #pragma unroll
    for (int c = 0; c < 4; ++c) { int n = base + c; if (n < NN) s += deg[n]; }
    sm[t] = s;
    __syncthreads();
    for (int off = 128; off > 0; off >>= 1) {
        if (t < off) sm[t] += sm[t + off];
        __syncthreads();
    }
    if (t == 0) partials[b] = sm[0];
}

__global__ void scan_top(int* __restrict__ partials, int* __restrict__ offs) {
    if (threadIdx.x == 0 && blockIdx.x == 0) {
        int run = 0;
        for (int i = 0; i < NCH; ++i) { int v = partials[i]; partials[i] = run; run += v; }
        offs[NN] = EE;
    }
}

__global__ __launch_bounds__(256) void scan_final(const int* __restrict__ deg,
                                                  const int* __restrict__ deg1,
                                                  const int* __restrict__ partials,
                                                  int* __restrict__ offs,
                                                  int* __restrict__ split,
                                                  int* __restrict__ curA,
                                                  int* __restrict__ curB) {
    __shared__ int sm[256];
    const int b = blockIdx.x, t = threadIdx.x;
    const int base = b * 1024 + t * 4;
    int v[4];
    int s = 0;
    #pragma unroll
    for (int c = 0; c < 4; ++c) {
        v[c] = (base + c < NN) ? deg[base + c] : 0;
        s += v[c];
    }
    sm[t] = s;
    __syncthreads();
    for (int off = 1; off < 256; off <<= 1) {
        int y = (t >= off) ? sm[t - off] : 0;
        __syncthreads();
        sm[t] += y;
        __syncthreads();
    }
    int run = partials[b] + sm[t] - s;    // exclusive prefix
    #pragma unroll
    for (int c = 0; c < 4; ++c) {
        int n = base + c;
        if (n < NN) {
            offs[n] = run;
            curA[n] = run;
            int sp = run + deg1[n];
            split[n] = sp;
            curB[n] = sp;
        }
        run += v[c];
    }
}

// ---------------- scatter edges: [src<C0 block | rest] within each dst bucket ----------------
__global__ void scatter2(const int* __restrict__ src, const int* __restrict__ dst,
                         int* __restrict__ curA, int* __restrict__ curB,
                         int* __restrict__ ssrc) {
    int i = (blockIdx.x * blockDim.x + threadIdx.x) * 2;
    int2 d = *(const int2*)(dst + i);
    int2 s = *(const int2*)(src + i);
    int p0 = (s.x < C0) ? atomicAdd(&curA[d.x], 1) : atomicAdd(&curB[d.x], 1);
    ssrc[p0] = s.x;
    int p1 = (s.y < C0) ? atomicAdd(&curA[d.y], 1) : atomicAdd(&curB[d.y], 1);
    ssrc[p1] = s.y;
}

// ---------------- unrolled gather: sum of h rows, 8 loads in flight ----------------
__device__ __forceinline__ float gather_row_sum(const float* __restrict__ base,
                                                const int* __restrict__ ssrc,
                                                int beg, int end, int lane) {
    float a0 = 0.f, a1 = 0.f, a2 = 0.f, a3 = 0.f, a4 = 0.f, a5 = 0.f, a6 = 0.f, a7 = 0.f;
    int j = beg;
    while (j < end && (j & 3)) { a0 += base[(size_t)ssrc[j] * HID + lane]; ++j; }
    for (; j + 8 <= end; j += 8) {
        int4 sa = *(const int4*)(ssrc + j);
        int4 sb = *(const int4*)(ssrc + j + 4);
        a0 += base[(size_t)sa.x * HID + lane];
        a1 += base[(size_t)sa.y * HID + lane];
        a2 += base[(size_t)sa.z * HID + lane];
        a3 += base[(size_t)sa.w * HID + lane];
        a4 += base[(size_t)sb.x * HID + lane];
        a5 += base[(size_t)sb.y * HID + lane];
        a6 += base[(size_t)sb.z * HID + lane];
        a7 += base[(size_t)sb.w * HID + lane];
    }
    if (j + 4 <= end) {
        int4 sa = *(const int4*)(ssrc + j);
        a0 += base[(size_t)sa.x * HID + lane];
        a1 += base[(size_t)sa.y * HID + lane];
        a2 += base[(size_t)sa.z * HID + lane];
        a3 += base[(size_t)sa.w * HID + lane];
        j += 4;
    }
    for (; j < end; ++j) a0 += base[(size_t)ssrc[j] * HID + lane];
    return ((a0 + a1) + (a2 + a3)) + ((a4 + a5) + (a6 + a7));
}

// ---------------- matvec: o[lane] = sum_j rb[j] * W[j][lane] ----------------
__device__ __forceinline__ float matvec64(const float* __restrict__ W,
                                          const float* __restrict__ rb, int lane) {
    float o = 0.f;
    #pragma unroll 16
    for (int j = 0; j < HID; ++j) o += rb[j] * W[j * HID + lane];
    return o;
}

// ---------------- K_A: spmm(h0, filtered) + k-matvec + emb + segment FC -> ht ----------------
__global__ __launch_bounds__(256) void k_a(const float* __restrict__ h,      // C0 x HID
                                           const int* __restrict__ offs,
                                           const int* __restrict__ split,
                                           const int* __restrict__ ssrc,
                                           const int* __restrict__ node_assign,
                                           const float* __restrict__ op_W,
                                           const float* __restrict__ op_b,
                                           const float* __restrict__ emb_W,
                                           const float* __restrict__ emb_b,
                                           const float* __restrict__ fc_W,
                                           const float* __restrict__ fc_b,
                                           float* __restrict__ ht) {
    __shared__ float rb[4][64];
    const int wv = threadIdx.x >> 6, lane = threadIdx.x & 63;
    const int n = blockIdx.x * 4 + wv;
    const int beg = offs[n], sp = split[n], endf = offs[n + 1];
    float acc = gather_row_sum(h, ssrc, beg, sp, lane);   // only src<C0 edges; rest are zero rows
    float a = acc / fmaxf((float)(endf - beg), 1.0f);     // normalize by FULL degree
    rb[wv][lane] = a;
    __syncthreads();
    const int k = node_assign[n];
    float o = matvec64(op_W + (size_t)k * HID * HID, rb[wv], lane);
    float hval = (n < C0) ? h[(size_t)n * HID + lane] : 0.f;
    float hatt = hval + o + op_b[k * HID + lane];
    float htv;
    if (n < C0) {               // block-uniform: C0 % 4 == 0
        htv = hatt;
    } else {
        const int si = (n < C0 + C1) ? 0 : 1;
        const int r = n - C0 - si * C1;
        hatt += emb_W[((size_t)si * C1 + r) * HID + lane] + emb_b[si * HID + lane];
        __syncthreads();
        rb[wv][lane] = hatt;
        __syncthreads();
        htv = matvec64(fc_W + (size_t)si * HID * HID, rb[wv], lane) + fc_b[si * HID + lane];
    }
    ht[(size_t)n * HID + lane] = htv;
}

// ---------------- K_B: spmm(ht, all) + gnn matvec + elu + logits -> out ----------------
__global__ __launch_bounds__(256) void k_b(const float* __restrict__ ht,
                                           const int* __restrict__ offs,
                                           const int* __restrict__ ssrc,
                                           const float* __restrict__ gnn_W,
                                           const float* __restrict__ gnn_b,
                                           const float* __restrict__ out_W,
                                           const float* __restrict__ out_b,
                                           float* __restrict__ out) {
    __shared__ float rb[4][64];
    const int wv = threadIdx.x >> 6, lane = threadIdx.x & 63;
    const int n = blockIdx.x * 4 + wv;
    const int beg = offs[n], endf = offs[n + 1];
    float acc = gather_row_sum(ht, ssrc, beg, endf, lane);
    float a = acc / fmaxf((float)(endf - beg), 1.0f);
    rb[wv][lane] = a;
    __syncthreads();
    float o = matvec64(gnn_W, rb[wv], lane) + gnn_b[lane];
    float emb = (o > 0.f) ? o : expm1f(o);   // elu
    out[(size_t)n * HID + lane] = emb;
    __syncthreads();
    rb[wv][lane] = emb;
    __syncthreads();
    // logits: 4 groups of 16 lanes each cover 16 j's, then cross-lane reduce
    const int c = lane & 15, q = lane >> 4;
    float lg = 0.f;
    #pragma unroll
    for (int jj = 0; jj < 16; ++jj) {
        int j = q * 16 + jj;
        lg += rb[wv][j] * out_W[j * NCLS + c];
    }
    lg += __shfl_down(lg, 32);
    lg += __shfl_down(lg, 16);
    if (lane < NCLS) {
        lg += out_b[lane];
        const size_t lbase = (size_t)NN * HID;
        out[lbase + (size_t)n * NCLS + lane] = lg;
        out[lbase + (size_t)NN * NCLS + (size_t)n * NCLS + lane] = lg;
    }
}

extern "C" void kernel_launch(void* const* d_in, const int* in_sizes, int n_in,
                              void* d_out, int out_size, void* d_ws, size_t ws_size,
                              hipStream_t stream) {
    const float* feats0 = (const float*)d_in[0];
    const float* W_pre  = (const float*)d_in[1];
    const float* b_pre  = (const float*)d_in[2];
    const float* emb_W  = (const float*)d_in[3];
    const float* emb_b  = (const float*)d_in[4];
    const float* op_W   = (const float*)d_in[5];
    const float* op_b   = (const float*)d_in[6];
    const float* fc_W   = (const float*)d_in[7];
    const float* fc_b   = (const float*)d_in[8];
    const float* gnn_W  = (const float*)d_in[9];
    const float* gnn_b  = (const float*)d_in[10];
    const float* out_W  = (const float*)d_in[11];
    const float* out_b  = (const float*)d_in[12];
    const int* src         = (const int*)d_in[13];
    const int* dst         = (const int*)d_in[14];
    const int* node_assign = (const int*)d_in[15];
    float* out = (float*)d_out;

    // workspace layout (~44.7 MB)
    float* h    = (float*)d_ws;                        // C0*HID
    float* ht   = h + (size_t)C0 * HID;                // NN*HID
    int* deg    = (int*)(ht + (size_t)NN * HID);       // NN
    int* deg1   = deg + NN;                            // NN
    int* offs   = deg1 + NN;                           // NN+1
    int* split  = offs + NN + 1;                       // NN
    int* curA   = split + NN;                          // NN
    int* curB   = curA + NN;                           // NN
    int* ssrc   = curB + NN;                           // EE
    int* partials = ssrc + EE;                         // NCH

    hipMemsetAsync(deg, 0, 2 * NN * sizeof(int), stream);   // deg + deg1

    pre_gemm<<<C0 / 64, 256, 0, stream>>>(feats0, W_pre, b_pre, h);
    count_deg2<<<EE / 2 / 256, 256, 0, stream>>>(src, dst, deg, deg1);
    scan_partial<<<NCH, 256, 0, stream>>>(deg, partials);
    scan_top<<<1, 64, 0, stream>>>(partials, offs);
    scan_final<<<NCH, 256, 0, stream>>>(deg, deg1, partials, offs, split, curA, curB);
    scatter2<<<EE / 2 / 256, 256, 0, stream>>>(src, dst, curA, curB, ssrc);
    k_a<<<NN / 4, 256, 0, stream>>>(h, offs, split, ssrc, node_assign,
                                    op_W, op_b, emb_W, emb_b, fc_W, fc_b, ht);
    k_b<<<NN / 4, 256, 0, stream>>>(ht, offs, ssrc, gnn_W, gnn_b, out_W, out_b, out);
}

// Round 3
// 359.323 us; speedup vs baseline: 1.9153x; 1.4230x over previous
//
#include <hip/hip_runtime.h>
#include <hip/hip_bf16.h>

#define NN   100000
#define C0   40000
#define C1   30000
#define C2   30000
#define HID  64
#define KK   8
#define EE   1600000
#define DIN  512
#define NCLS 16
#define NB   196      // ceil(100000/512) coarse dst buckets
#define BKE  2048     // edges per block in coarse pass
#define GR1  782      // ceil(EE/BKE)

// ---------------- pre GEMM: h[0:40000] = feats0 @ W_pre + b_pre ----------------
__global__ __launch_bounds__(256) void pre_gemm(const float* __restrict__ A,
                                                const float* __restrict__ W,
                                                const float* __restrict__ b,
                                                float* __restrict__ h) {
    __shared__ float As[64][65];
    __shared__ float Bs[64][64];
    const int tid = threadIdx.x;
    const int row0 = blockIdx.x * 64;
    const int tx = tid & 15, ty = tid >> 4;
    float acc[4][4] = {};
    for (int k0 = 0; k0 < DIN; k0 += 64) {
        for (int i = tid; i < 64 * 16; i += 256) {
            int r = i >> 4, c4 = i & 15;
            float4 v = *(const float4*)(A + (size_t)(row0 + r) * DIN + k0 + c4 * 4);
            As[r][c4 * 4 + 0] = v.x; As[r][c4 * 4 + 1] = v.y;
            As[r][c4 * 4 + 2] = v.z; As[r][c4 * 4 + 3] = v.w;
        }
        for (int i = tid; i < 64 * 16; i += 256) {
            int r = i >> 4, c4 = i & 15;
            *(float4*)(&Bs[r][c4 * 4]) = *(const float4*)(W + (size_t)(k0 + r) * HID + c4 * 4);
        }
        __syncthreads();
        for (int kk = 0; kk < 64; ++kk) {
            float a0 = As[ty * 4 + 0][kk], a1 = As[ty * 4 + 1][kk];
            float a2 = As[ty * 4 + 2][kk], a3 = As[ty * 4 + 3][kk];
            float4 bv = *(const float4*)(&Bs[kk][tx * 4]);
            acc[0][0] += a0 * bv.x; acc[0][1] += a0 * bv.y; acc[0][2] += a0 * bv.z; acc[0][3] += a0 * bv.w;
            acc[1][0] += a1 * bv.x; acc[1][1] += a1 * bv.y; acc[1][2] += a1 * bv.z; acc[1][3] += a1 * bv.w;
            acc[2][0] += a2 * bv.x; acc[2][1] += a2 * bv.y; acc[2][2] += a2 * bv.z; acc[2][3] += a2 * bv.w;
            acc[3][0] += a3 * bv.x; acc[3][1] += a3 * bv.y; acc[3][2] += a3 * bv.z; acc[3][3] += a3 * bv.w;
        }
        __syncthreads();
    }
    float4 bb = *(const float4*)(b + tx * 4);
    for (int r = 0; r < 4; ++r) {
        float4 o;
        o.x = acc[r][0] + bb.x; o.y = acc[r][1] + bb.y;
        o.z = acc[r][2] + bb.z; o.w = acc[r][3] + bb.w;
        *(float4*)(h + (size_t)(row0 + ty * 4 + r) * HID + tx * 4) = o;
    }
}

// ---------------- r0: coarse bucket counts (fire-and-forget atomics) ----------------
__global__ __launch_bounds__(256) void bucket_count(const int* __restrict__ dst,
                                                    int* __restrict__ bcnt) {
    __shared__ int hh[NB];
    for (int i = threadIdx.x; i < NB; i += 256) hh[i] = 0;
    __syncthreads();
    const int base = blockIdx.x * BKE;
    for (int u = 0; u < BKE / 256; ++u) {
        int t = base + threadIdx.x + u * 256;
        if (t < EE) atomicAdd(&hh[dst[t] >> 9], 1);
    }
    __syncthreads();
    for (int i = threadIdx.x; i < NB; i += 256) {
        int c = hh[i];
        if (c) atomicAdd(&bcnt[i], c);
    }
}

// ---------------- tiny scan over NB buckets ----------------
__global__ void bucket_scan(const int* __restrict__ bcnt, int* __restrict__ bbase,
                            int* __restrict__ bcur, int* __restrict__ offs) {
    if (threadIdx.x == 0 && blockIdx.x == 0) {
        int run = 0;
        for (int i = 0; i < NB; ++i) { bbase[i] = run; bcur[i] = run; run += bcnt[i]; }
        offs[NN] = EE;
    }
}

// ---------------- r1: coarse scatter into dst-bucketed edge buffer ----------------
__global__ __launch_bounds__(256) void coarse_scatter(const int* __restrict__ src,
                                                      const int* __restrict__ dst,
                                                      int* __restrict__ bcur,
                                                      uint2* __restrict__ ebuf) {
    __shared__ int hcnt[NB];
    __shared__ int gbase[NB];
    for (int i = threadIdx.x; i < NB; i += 256) hcnt[i] = 0;
    __syncthreads();
    const int base = blockIdx.x * BKE;
    int mys[8], myd[8], mybin[8], myrank[8];
    #pragma unroll
    for (int u = 0; u < 8; ++u) {
        int t = base + threadIdx.x + u * 256;
        if (t < EE) {
            int d = dst[t];
            mys[u] = src[t]; myd[u] = d; mybin[u] = d >> 9;
            myrank[u] = atomicAdd(&hcnt[mybin[u]], 1);
        } else mybin[u] = -1;
    }
    __syncthreads();
    for (int i = threadIdx.x; i < NB; i += 256) {
        int c = hcnt[i];
        gbase[i] = c ? atomicAdd(&bcur[i], c) : 0;
    }
    __syncthreads();
    #pragma unroll
    for (int u = 0; u < 8; ++u) {
        if (mybin[u] >= 0) {
            uint2 e; e.x = (unsigned)mys[u]; e.y = (unsigned)myd[u];
            ebuf[gbase[mybin[u]] + myrank[u]] = e;
        }
    }
}

// ---------------- r2: per-bucket exact CSR (LDS atomics only) ----------------
__global__ __launch_bounds__(256) void fine_scatter(const uint2* __restrict__ ebuf,
                                                    const int* __restrict__ bbase,
                                                    const int* __restrict__ bend,
                                                    int* __restrict__ offs,
                                                    int* __restrict__ split,
                                                    int* __restrict__ ssrc) {
    __shared__ int hist[1024];
    __shared__ int lofs[1024];
    __shared__ int sm[256];
    const int t = threadIdx.x, b = blockIdx.x;
    const int beg = bbase[b], end = bend[b];
    for (int i = t; i < 1024; i += 256) hist[i] = 0;
    __syncthreads();
    for (int j = beg + t; j < end; j += 256) {
        uint2 e = ebuf[j];
        int bin = ((e.y & 511) << 1) | (e.x < C0 ? 0 : 1);
        atomicAdd(&hist[bin], 1);
    }
    __syncthreads();
    // exclusive scan of 1024 bins
    int v0 = hist[4 * t], v1 = hist[4 * t + 1], v2 = hist[4 * t + 2], v3 = hist[4 * t + 3];
    int ts = v0 + v1 + v2 + v3;
    sm[t] = ts;
    __syncthreads();
    for (int off = 1; off < 256; off <<= 1) {
        int y = (t >= off) ? sm[t - off] : 0;
        __syncthreads();
        sm[t] += y;
        __syncthreads();
    }
    int pre = sm[t] - ts;
    lofs[4 * t] = pre; lofs[4 * t + 1] = pre + v0;
    lofs[4 * t + 2] = pre + v0 + v1; lofs[4 * t + 3] = pre + v0 + v1 + v2;
    __syncthreads();
    const int d0 = b * 512;
    for (int i = t; i < 512; i += 256) {
        int n = d0 + i;
        if (n < NN) {
            offs[n]  = beg + lofs[2 * i];
            split[n] = beg + lofs[2 * i + 1];
        }
    }
    __syncthreads();
    for (int j = beg + t; j < end; j += 256) {
        uint2 e = ebuf[j];
        int bin = ((e.y & 511) << 1) | (e.x < C0 ? 0 : 1);
        int pos = beg + atomicAdd(&lofs[bin], 1);
        ssrc[pos] = (int)e.x;
    }
}

// ---------------- gather: 4 edges/step (q=edge slot, c4=float4 col), 8 in flight ----------------
__device__ __forceinline__ float4 gather4(const float* __restrict__ base,
                                          const int* __restrict__ ssrc,
                                          int beg, int end, int q, int c4) {
    float4 a0 = {0.f, 0.f, 0.f, 0.f}, a1 = {0.f, 0.f, 0.f, 0.f};
    int j = beg + q;
    for (; j + 4 < end; j += 8) {
        int s0 = ssrc[j];
        int s1 = ssrc[j + 4];
        float4 u = *(const float4*)(base + (size_t)s0 * HID + c4 * 4);
        float4 v = *(const float4*)(base + (size_t)s1 * HID + c4 * 4);
        a0.x += u.x; a0.y += u.y; a0.z += u.z; a0.w += u.w;
        a1.x += v.x; a1.y += v.y; a1.z += v.z; a1.w += v.w;
    }
    if (j < end) {
        int s0 = ssrc[j];
        float4 u = *(const float4*)(base + (size_t)s0 * HID + c4 * 4);
        a0.x += u.x; a0.y += u.y; a0.z += u.z; a0.w += u.w;
    }
    a0.x += a1.x; a0.y += a1.y; a0.z += a1.z; a0.w += a1.w;
    a0.x += __shfl_down(a0.x, 32); a0.y += __shfl_down(a0.y, 32);
    a0.z += __shfl_down(a0.z, 32); a0.w += __shfl_down(a0.w, 32);
    a0.x += __shfl_down(a0.x, 16); a0.y += __shfl_down(a0.y, 16);
    a0.z += __shfl_down(a0.z, 16); a0.w += __shfl_down(a0.w, 16);
    return a0;   // valid in lanes 0..15
}

// matvec: lane (q,c4) partial over j in [q*16,q*16+16); returns float4, valid lanes 0..15 after reduce
__device__ __forceinline__ float4 matvec_f4(const float* __restrict__ W,
                                            const float* __restrict__ rb, int q, int c4) {
    float4 o = {0.f, 0.f, 0.f, 0.f};
    #pragma unroll
    for (int jj = 0; jj < 16; ++jj) {
        int j = q * 16 + jj;
        float r = rb[j];
        float4 w = *(const float4*)(W + (size_t)j * HID + c4 * 4);
        o.x += r * w.x; o.y += r * w.y; o.z += r * w.z; o.w += r * w.w;
    }
    o.x += __shfl_down(o.x, 32); o.y += __shfl_down(o.y, 32);
    o.z += __shfl_down(o.z, 32); o.w += __shfl_down(o.w, 32);
    o.x += __shfl_down(o.x, 16); o.y += __shfl_down(o.y, 16);
    o.z += __shfl_down(o.z, 16); o.w += __shfl_down(o.w, 16);
    return o;
}

// ---------------- K_A: spmm(h0, filtered) + k-matvec + emb + segment FC -> ht ----------------
__global__ __launch_bounds__(256) void k_a(const float* __restrict__ h,
                                           const int* __restrict__ offs,
                                           const int* __restrict__ split,
                                           const int* __restrict__ ssrc,
                                           const int* __restrict__ node_assign,
                                           const float* __restrict__ op_W,
                                           const float* __restrict__ op_b,
                                           const float* __restrict__ emb_W,
                                           const float* __restrict__ emb_b,
                                           const float* __restrict__ fc_W,
                                           const float* __restrict__ fc_b,
                                           float* __restrict__ ht) {
    __shared__ float rb[4][64];
    const int wv = threadIdx.x >> 6, lane = threadIdx.x & 63;
    const int c4 = lane & 15, q = lane >> 4;
    const int n = blockIdx.x * 4 + wv;
    const int beg = offs[n], sp = split[n], endf = offs[n + 1];
    float4 acc = gather4(h, ssrc, beg, sp, q, c4);
    const float inv = 1.0f / fmaxf((float)(endf - beg), 1.0f);
    if (lane < 16) {
        acc.x *= inv; acc.y *= inv; acc.z *= inv; acc.w *= inv;
        *(float4*)(&rb[wv][c4 * 4]) = acc;
    }
    __syncthreads();
    const int k = node_assign[n];
    float4 o = matvec_f4(op_W + (size_t)k * HID * HID, rb[wv], q, c4);
    if (n < C0) {                       // block-uniform (C0 % 4 == 0)
        if (lane < 16) {
            float4 hv = *(const float4*)(h + (size_t)n * HID + c4 * 4);
            float4 ob = *(const float4*)(op_b + (size_t)k * HID + c4 * 4);
            float4 r;
            r.x = hv.x + o.x + ob.x; r.y = hv.y + o.y + ob.y;
            r.z = hv.z + o.z + ob.z; r.w = hv.w + o.w + ob.w;
            *(float4*)(ht + (size_t)n * HID + c4 * 4) = r;
        }
        __syncthreads();                // keep barriers uniform with else-branch count? no second use
    } else {
        const int si = (n < C0 + C1) ? 0 : 1;
        const int rr = n - C0 - si * C1;
        if (lane < 16) {
            float4 ob = *(const float4*)(op_b + (size_t)k * HID + c4 * 4);
            float4 ew = *(const float4*)(emb_W + ((size_t)si * C1 + rr) * HID + c4 * 4);
            float4 eb = *(const float4*)(emb_b + (size_t)si * HID + c4 * 4);
            float4 hatt;
            hatt.x = o.x + ob.x + ew.x + eb.x; hatt.y = o.y + ob.y + ew.y + eb.y;
            hatt.z = o.z + ob.z + ew.z + eb.z; hatt.w = o.w + ob.w + ew.w + eb.w;
            *(float4*)(&rb[wv][c4 * 4]) = hatt;
        }
        __syncthreads();
        float4 o2 = matvec_f4(fc_W + (size_t)si * HID * HID, rb[wv], q, c4);
        if (lane < 16) {
            float4 fb = *(const float4*)(fc_b + (size_t)si * HID + c4 * 4);
            float4 r;
            r.x = o2.x + fb.x; r.y = o2.y + fb.y;
            r.z = o2.z + fb.z; r.w = o2.w + fb.w;
            *(float4*)(ht + (size_t)n * HID + c4 * 4) = r;
        }
    }
}

// ---------------- K_B: spmm(ht, all) + gnn matvec (LDS W) + elu + logits -> out ----------------
__global__ __launch_bounds__(256) void k_b(const float* __restrict__ ht,
                                           const int* __restrict__ offs,
                                           const int* __restrict__ ssrc,
                                           const float* __restrict__ gnn_W,
                                           const float* __restrict__ gnn_b,
                                           const float* __restrict__ out_W,
                                           const float* __restrict__ out_b,
                                           float* __restrict__ out) {
    __shared__ float Wg[HID * HID];
    __shared__ float Wo[HID * NCLS];
    __shared__ float rb[4][64];
    const int tid = threadIdx.x;
    for (int i = tid; i < HID * HID / 4; i += 256)
        *(float4*)(&Wg[i * 4]) = *(const float4*)(gnn_W + i * 4);
    for (int i = tid; i < HID * NCLS / 4; i += 256)
        *(float4*)(&Wo[i * 4]) = *(const float4*)(out_W + i * 4);
    __syncthreads();
    const int wv = tid >> 6, lane = tid & 63;
    const int c4 = lane & 15, q = lane >> 4;
    const int n = blockIdx.x * 4 + wv;
    const int beg = offs[n], endf = offs[n + 1];
    float4 acc = gather4(ht, ssrc, beg, endf, q, c4);
    const float inv = 1.0f / fmaxf((float)(endf - beg), 1.0f);
    if (lane < 16) {
        acc.x *= inv; acc.y *= inv; acc.z *= inv; acc.w *= inv;
        *(float4*)(&rb[wv][c4 * 4]) = acc;
    }
    __syncthreads();
    float4 o = matvec_f4(Wg, rb[wv], q, c4);
    if (lane < 16) {
        float4 gb = *(const float4*)(gnn_b + c4 * 4);
        o.x += gb.x; o.y += gb.y; o.z += gb.z; o.w += gb.w;
        o.x = (o.x > 0.f) ? o.x : expm1f(o.x);
        o.y = (o.y > 0.f) ? o.y : expm1f(o.y);
        o.z = (o.z > 0.f) ? o.z : expm1f(o.z);
        o.w = (o.w > 0.f) ? o.w : expm1f(o.w);
        *(float4*)(out + (size_t)n * HID + c4 * 4) = o;
        *(float4*)(&rb[wv][c4 * 4]) = o;
    }
    __syncthreads();
    // logits: class c4, j-groups q
    float lg = 0.f;
    #pragma unroll
    for (int jj = 0; jj < 16; ++jj) {
        int j = q * 16 + jj;
        lg += rb[wv][j] * Wo[j * NCLS + c4];
    }
    lg += __shfl_down(lg, 32);
    lg += __shfl_down(lg, 16);
    if (lane < 16) {
        lg += out_b[c4];
        const size_t lbase = (size_t)NN * HID;
        out[lbase + (size_t)n * NCLS + c4] = lg;
        out[lbase + (size_t)NN * NCLS + (size_t)n * NCLS + c4] = lg;
    }
}

extern "C" void kernel_launch(void* const* d_in, const int* in_sizes, int n_in,
                              void* d_out, int out_size, void* d_ws, size_t ws_size,
                              hipStream_t stream) {
    const float* feats0 = (const float*)d_in[0];
    const float* W_pre  = (const float*)d_in[1];
    const float* b_pre  = (const float*)d_in[2];
    const float* emb_W  = (const float*)d_in[3];
    const float* emb_b  = (const float*)d_in[4];
    const float* op_W   = (const float*)d_in[5];
    const float* op_b   = (const float*)d_in[6];
    const float* fc_W   = (const float*)d_in[7];
    const float* fc_b   = (const float*)d_in[8];
    const float* gnn_W  = (const float*)d_in[9];
    const float* gnn_b  = (const float*)d_in[10];
    const float* out_W  = (const float*)d_in[11];
    const float* out_b  = (const float*)d_in[12];
    const int* src         = (const int*)d_in[13];
    const int* dst         = (const int*)d_in[14];
    const int* node_assign = (const int*)d_in[15];
    float* out = (float*)d_out;

    // workspace layout (~56 MB); ebuf 8B-aligned (preceded by even float counts)
    float* h    = (float*)d_ws;                        // C0*HID
    float* ht   = h + (size_t)C0 * HID;                // NN*HID
    uint2* ebuf = (uint2*)(ht + (size_t)NN * HID);     // EE uint2
    int* ssrc   = (int*)(ebuf + EE);                   // EE
    int* offs   = ssrc + EE;                           // NN+1
    int* split  = offs + NN + 1;                       // NN
    int* bbase  = split + NN;                          // NB
    int* bcur   = bbase + NB;                          // NB
    int* bcnt   = bcur + NB;                           // NB

    hipMemsetAsync(bcnt, 0, NB * sizeof(int), stream);

    pre_gemm<<<C0 / 64, 256, 0, stream>>>(feats0, W_pre, b_pre, h);
    bucket_count<<<GR1, 256, 0, stream>>>(dst, bcnt);
    bucket_scan<<<1, 64, 0, stream>>>(bcnt, bbase, bcur, offs);
    coarse_scatter<<<GR1, 256, 0, stream>>>(src, dst, bcur, ebuf);
    fine_scatter<<<NB, 256, 0, stream>>>(ebuf, bbase, bcur, offs, split, ssrc);
    k_a<<<NN / 4, 256, 0, stream>>>(h, offs, split, ssrc, node_assign,
                                    op_W, op_b, emb_W, emb_b, fc_W, fc_b, ht);
    k_b<<<NN / 4, 256, 0, stream>>>(ht, offs, ssrc, gnn_W, gnn_b, out_W, out_b, out);
}

// Round 4
// 305.867 us; speedup vs baseline: 2.2500x; 1.1748x over previous
//
#include <hip/hip_runtime.h>
#include <hip/hip_bf16.h>

#define NN   100000
#define C0   40000
#define C1   30000
#define C2   30000
#define HID  64
#define KK   8
#define EE   1600000
#define DIN  512
#define NCLS 16
#define NB   196      // ceil(100000/512) coarse dst buckets
#define BKE  2048     // edges per block in coarse pass
#define GR1  782      // ceil(EE/BKE)
#define NBC  1568     // KK*NB node-bucket counts
#define MAXT 1571     // upper bound on op-GEMM tiles
#define FCT  469      // ceil(30000/64) fc tiles per segment
#define GNT  1563     // ceil(100000/64) gnn tiles

// ---------------- pre GEMM: h[0:40000] = feats0 @ W_pre + b_pre ----------------
__global__ __launch_bounds__(256) void pre_gemm(const float* __restrict__ A,
                                                const float* __restrict__ W,
                                                const float* __restrict__ b,
                                                float* __restrict__ h) {
    __shared__ float As[64][65];
    __shared__ float Bs[64][64];
    const int tid = threadIdx.x;
    const int row0 = blockIdx.x * 64;
    const int tx = tid & 15, ty = tid >> 4;
    float acc[4][4] = {};
    for (int k0 = 0; k0 < DIN; k0 += 64) {
        for (int i = tid; i < 64 * 16; i += 256) {
            int r = i >> 4, c4 = i & 15;
            float4 v = *(const float4*)(A + (size_t)(row0 + r) * DIN + k0 + c4 * 4);
            As[r][c4 * 4 + 0] = v.x; As[r][c4 * 4 + 1] = v.y;
            As[r][c4 * 4 + 2] = v.z; As[r][c4 * 4 + 3] = v.w;
        }
        for (int i = tid; i < 64 * 16; i += 256) {
            int r = i >> 4, c4 = i & 15;
            *(float4*)(&Bs[r][c4 * 4]) = *(const float4*)(W + (size_t)(k0 + r) * HID + c4 * 4);
        }
        __syncthreads();
        for (int kk = 0; kk < 64; ++kk) {
            float a0 = As[ty * 4 + 0][kk], a1 = As[ty * 4 + 1][kk];
            float a2 = As[ty * 4 + 2][kk], a3 = As[ty * 4 + 3][kk];
            float4 bv = *(const float4*)(&Bs[kk][tx * 4]);
            acc[0][0] += a0 * bv.x; acc[0][1] += a0 * bv.y; acc[0][2] += a0 * bv.z; acc[0][3] += a0 * bv.w;
            acc[1][0] += a1 * bv.x; acc[1][1] += a1 * bv.y; acc[1][2] += a1 * bv.z; acc[1][3] += a1 * bv.w;
            acc[2][0] += a2 * bv.x; acc[2][1] += a2 * bv.y; acc[2][2] += a2 * bv.z; acc[2][3] += a2 * bv.w;
            acc[3][0] += a3 * bv.x; acc[3][1] += a3 * bv.y; acc[3][2] += a3 * bv.z; acc[3][3] += a3 * bv.w;
        }
        __syncthreads();
    }
    float4 bb = *(const float4*)(b + tx * 4);
    for (int r = 0; r < 4; ++r) {
        float4 o;
        o.x = acc[r][0] + bb.x; o.y = acc[r][1] + bb.y;
        o.z = acc[r][2] + bb.z; o.w = acc[r][3] + bb.w;
        *(float4*)(h + (size_t)(row0 + ty * 4 + r) * HID + tx * 4) = o;
    }
}

// ---------------- r0: coarse bucket counts ----------------
__global__ __launch_bounds__(256) void bucket_count(const int* __restrict__ dst,
                                                    int* __restrict__ bcnt) {
    __shared__ int hh[NB];
    for (int i = threadIdx.x; i < NB; i += 256) hh[i] = 0;
    __syncthreads();
    const int base = blockIdx.x * BKE;
    for (int u = 0; u < BKE / 256; ++u) {
        int t = base + threadIdx.x + u * 256;
        if (t < EE) atomicAdd(&hh[dst[t] >> 9], 1);
    }
    __syncthreads();
    for (int i = threadIdx.x; i < NB; i += 256) {
        int c = hh[i];
        if (c) atomicAdd(&bcnt[i], c);
    }
}

__global__ void bucket_scan(const int* __restrict__ bcnt, int* __restrict__ bbase,
                            int* __restrict__ bcur, int* __restrict__ offs) {
    if (threadIdx.x == 0 && blockIdx.x == 0) {
        int run = 0;
        for (int i = 0; i < NB; ++i) { bbase[i] = run; bcur[i] = run; run += bcnt[i]; }
        offs[NN] = EE;
    }
}

// ---------------- r1: coarse scatter ----------------
__global__ __launch_bounds__(256) void coarse_scatter(const int* __restrict__ src,
                                                      const int* __restrict__ dst,
                                                      int* __restrict__ bcur,
                                                      uint2* __restrict__ ebuf) {
    __shared__ int hcnt[NB];
    __shared__ int gbase[NB];
    for (int i = threadIdx.x; i < NB; i += 256) hcnt[i] = 0;
    __syncthreads();
    const int base = blockIdx.x * BKE;
    int mys[8], myd[8], mybin[8], myrank[8];
    #pragma unroll
    for (int u = 0; u < 8; ++u) {
        int t = base + threadIdx.x + u * 256;
        if (t < EE) {
            int d = dst[t];
            mys[u] = src[t]; myd[u] = d; mybin[u] = d >> 9;
            myrank[u] = atomicAdd(&hcnt[mybin[u]], 1);
        } else mybin[u] = -1;
    }
    __syncthreads();
    for (int i = threadIdx.x; i < NB; i += 256) {
        int c = hcnt[i];
        gbase[i] = c ? atomicAdd(&bcur[i], c) : 0;
    }
    __syncthreads();
    #pragma unroll
    for (int u = 0; u < 8; ++u) {
        if (mybin[u] >= 0) {
            uint2 e; e.x = (unsigned)mys[u]; e.y = (unsigned)myd[u];
            ebuf[gbase[mybin[u]] + myrank[u]] = e;
        }
    }
}

// ---------------- r2: per-bucket exact CSR ----------------
__global__ __launch_bounds__(256) void fine_scatter(const uint2* __restrict__ ebuf,
                                                    const int* __restrict__ bbase,
                                                    const int* __restrict__ bend,
                                                    int* __restrict__ offs,
                                                    int* __restrict__ split,
                                                    int* __restrict__ ssrc) {
    __shared__ int hist[1024];
    __shared__ int lofs[1024];
    __shared__ int sm[256];
    const int t = threadIdx.x, b = blockIdx.x;
    const int beg = bbase[b], end = bend[b];
    for (int i = t; i < 1024; i += 256) hist[i] = 0;
    __syncthreads();
    for (int j = beg + t; j < end; j += 256) {
        uint2 e = ebuf[j];
        int bin = ((e.y & 511) << 1) | (e.x < C0 ? 0 : 1);
        atomicAdd(&hist[bin], 1);
    }
    __syncthreads();
    int v0 = hist[4 * t], v1 = hist[4 * t + 1], v2 = hist[4 * t + 2], v3 = hist[4 * t + 3];
    int ts = v0 + v1 + v2 + v3;
    sm[t] = ts;
    __syncthreads();
    for (int off = 1; off < 256; off <<= 1) {
        int y = (t >= off) ? sm[t - off] : 0;
        __syncthreads();
        sm[t] += y;
        __syncthreads();
    }
    int pre = sm[t] - ts;
    lofs[4 * t] = pre; lofs[4 * t + 1] = pre + v0;
    lofs[4 * t + 2] = pre + v0 + v1; lofs[4 * t + 3] = pre + v0 + v1 + v2;
    __syncthreads();
    const int d0 = b * 512;
    for (int i = t; i < 512; i += 256) {
        int n = d0 + i;
        if (n < NN) {
            offs[n]  = beg + lofs[2 * i];
            split[n] = beg + lofs[2 * i + 1];
        }
    }
    __syncthreads();
    for (int j = beg + t; j < end; j += 256) {
        uint2 e = ebuf[j];
        int bin = ((e.y & 511) << 1) | (e.x < C0 ? 0 : 1);
        int pos = beg + atomicAdd(&lofs[bin], 1);
        ssrc[pos] = (int)e.x;
    }
}

// ---------------- node buckets by k: count ----------------
__global__ __launch_bounds__(256) void nb_count(const int* __restrict__ na,
                                                int* __restrict__ nbc) {
    __shared__ int hist[KK];
    const int t = threadIdx.x, b = blockIdx.x;
    if (t < KK) hist[t] = 0;
    __syncthreads();
    #pragma unroll
    for (int u = 0; u < 2; ++u) {
        int n = b * 512 + t + u * 256;
        if (n < NN) atomicAdd(&hist[na[n]], 1);
    }
    __syncthreads();
    if (t < KK) nbc[t * NB + b] = hist[t];
}

// ---------------- node buckets: scan + tile map ----------------
__global__ __launch_bounds__(256) void nb_scan(const int* __restrict__ nbc,
                                               int* __restrict__ gbase,
                                               int* __restrict__ koff,
                                               int* __restrict__ tmap_b,
                                               int* __restrict__ tmap_s) {
    __shared__ int sm[256];
    __shared__ int carry;
    __shared__ int tl[KK];
    const int t = threadIdx.x;
    if (t == 0) carry = 0;
    for (int i = t; i < MAXT; i += 256) tmap_b[i] = -1;
    __syncthreads();
    for (int c = 0; c < 7; ++c) {
        int i = c * 256 + t;
        int v = (i < NBC) ? nbc[i] : 0;
        sm[t] = v;
        __syncthreads();
        for (int off = 1; off < 256; off <<= 1) {
            int y = (t >= off) ? sm[t - off] : 0;
            __syncthreads();
            sm[t] += y;
            __syncthreads();
        }
        int base = carry;
        int excl = base + sm[t] - v;
        if (i < NBC) {
            gbase[i] = excl;
            if ((i % NB) == 0) koff[i / NB] = excl;
        }
        __syncthreads();
        if (t == 255) carry = base + sm[255];
        __syncthreads();
    }
    if (t == 0) {
        koff[KK] = NN;
        int run = 0;
        for (int k = 0; k < KK; ++k) tl[k] = 0;   // init
    }
    __syncthreads();
    if (t == 0) {
        int run = 0;
        for (int k = 0; k < KK; ++k) {
            tl[k] = run;
            int cnt = ((k == KK - 1) ? NN : koff[k + 1]) - koff[k];
            run += (cnt + 63) / 64;
        }
    }
    __syncthreads();
    if (t < KK) {
        int k = t;
        int kb = koff[k];
        int ke = (k == KK - 1) ? NN : koff[k + 1];
        int nt = (ke - kb + 63) / 64;
        for (int tt = 0; tt < nt; ++tt) {
            tmap_b[tl[k] + tt] = k;
            tmap_s[tl[k] + tt] = kb + tt * 64;
        }
    }
}

// ---------------- node buckets: scatter ----------------
__global__ __launch_bounds__(256) void nb_scatter(const int* __restrict__ na,
                                                  const int* __restrict__ gbase,
                                                  int* __restrict__ perm) {
    __shared__ int hist[KK];
    __shared__ int gb[KK];
    const int t = threadIdx.x, b = blockIdx.x;
    if (t < KK) { hist[t] = 0; gb[t] = gbase[t * NB + b]; }
    __syncthreads();
    #pragma unroll
    for (int u = 0; u < 2; ++u) {
        int n = b * 512 + t + u * 256;
        if (n < NN) {
            int k = na[n];
            int r = atomicAdd(&hist[k], 1);
            perm[gb[k] + r] = n;
        }
    }
}

// ---------------- spmm: 16-lane group per node ----------------
__global__ __launch_bounds__(256) void spmm(const float* __restrict__ hrows,
                                            const int* __restrict__ offs,
                                            const int* __restrict__ splt,
                                            const int* __restrict__ ssrc,
                                            float* __restrict__ agg) {
    const int t = threadIdx.x;
    const int g = t >> 4, c4 = t & 15;
    const int n = blockIdx.x * 16 + g;
    const int beg = offs[n], endf = offs[n + 1];
    const int ge = splt ? splt[n] : endf;         // filtered end (or full)
    float4 a0 = {0.f, 0.f, 0.f, 0.f}, a1 = {0.f, 0.f, 0.f, 0.f};
    int j = beg;
    for (; j + 2 <= ge; j += 2) {
        int s0 = ssrc[j], s1 = ssrc[j + 1];
        float4 u = *(const float4*)(hrows + (size_t)s0 * HID + c4 * 4);
        float4 v = *(const float4*)(hrows + (size_t)s1 * HID + c4 * 4);
        a0.x += u.x; a0.y += u.y; a0.z += u.z; a0.w += u.w;
        a1.x += v.x; a1.y += v.y; a1.z += v.z; a1.w += v.w;
    }
    if (j < ge) {
        int s0 = ssrc[j];
        float4 u = *(const float4*)(hrows + (size_t)s0 * HID + c4 * 4);
        a0.x += u.x; a0.y += u.y; a0.z += u.z; a0.w += u.w;
    }
    const float inv = 1.0f / fmaxf((float)(endf - beg), 1.0f);
    float4 r;
    r.x = (a0.x + a1.x) * inv; r.y = (a0.y + a1.y) * inv;
    r.z = (a0.z + a1.z) * inv; r.w = (a0.w + a1.w) * inv;
    *(float4*)(agg + (size_t)n * HID + c4 * 4) = r;
}

// ---------------- shared 64x64x64 GEMM core ----------------
__device__ __forceinline__ void gemm64(const float As[64][65], const float Bs[64][64],
                                       float acc[4][4], int tx, int ty) {
    for (int kk = 0; kk < 64; ++kk) {
        float a0 = As[ty * 4 + 0][kk], a1 = As[ty * 4 + 1][kk];
        float a2 = As[ty * 4 + 2][kk], a3 = As[ty * 4 + 3][kk];
        float4 bv = *(const float4*)(&Bs[kk][tx * 4]);
        acc[0][0] += a0 * bv.x; acc[0][1] += a0 * bv.y; acc[0][2] += a0 * bv.z; acc[0][3] += a0 * bv.w;
        acc[1][0] += a1 * bv.x; acc[1][1] += a1 * bv.y; acc[1][2] += a1 * bv.z; acc[1][3] += a1 * bv.w;
        acc[2][0] += a2 * bv.x; acc[2][1] += a2 * bv.y; acc[2][2] += a2 * bv.z; acc[2][3] += a2 * bv.w;
        acc[3][0] += a3 * bv.x; acc[3][1] += a3 * bv.y; acc[3][2] += a3 * bv.z; acc[3][3] += a3 * bv.w;
    }
}

// ---------------- op GEMM: k-bucketed tiles, hatt -> ht ----------------
__global__ __launch_bounds__(256) void op_gemm(const float* __restrict__ agg,
                                               const float* __restrict__ h,
                                               const int* __restrict__ perm,
                                               const int* __restrict__ koff,
                                               const int* __restrict__ tmap_b,
                                               const int* __restrict__ tmap_s,
                                               const float* __restrict__ op_W,
                                               const float* __restrict__ op_b,
                                               const float* __restrict__ emb_W,
                                               const float* __restrict__ emb_b,
                                               float* __restrict__ ht) {
    __shared__ float As[64][65];
    __shared__ float Bs[64][64];
    __shared__ int idx[64];
    const int bk = tmap_b[blockIdx.x];
    if (bk < 0) return;
    const int start = tmap_s[blockIdx.x];
    const int kend = koff[bk + 1];
    const int tid = threadIdx.x;
    if (tid < 64) {
        int p = start + tid;
        idx[tid] = (p < kend) ? perm[p] : -1;
    }
    __syncthreads();
    for (int i = tid; i < 64 * 16; i += 256) {
        int r = i >> 4, c4 = i & 15;
        int n = idx[r];
        float4 v = {0.f, 0.f, 0.f, 0.f};
        if (n >= 0) v = *(const float4*)(agg + (size_t)n * HID + c4 * 4);
        As[r][c4 * 4 + 0] = v.x; As[r][c4 * 4 + 1] = v.y;
        As[r][c4 * 4 + 2] = v.z; As[r][c4 * 4 + 3] = v.w;
    }
    for (int i = tid; i < 64 * 16; i += 256) {
        int r = i >> 4, c4 = i & 15;
        *(float4*)(&Bs[r][c4 * 4]) = *(const float4*)(op_W + (size_t)bk * HID * HID + (size_t)r * HID + c4 * 4);
    }
    __syncthreads();
    const int tx = tid & 15, ty = tid >> 4;
    float acc[4][4] = {};
    gemm64(As, Bs, acc, tx, ty);
    float4 ob = *(const float4*)(op_b + (size_t)bk * HID + tx * 4);
    #pragma unroll
    for (int rr = 0; rr < 4; ++rr) {
        int n = idx[ty * 4 + rr];
        if (n < 0) continue;
        float4 v;
        v.x = acc[rr][0] + ob.x; v.y = acc[rr][1] + ob.y;
        v.z = acc[rr][2] + ob.z; v.w = acc[rr][3] + ob.w;
        if (n < C0) {
            float4 hv = *(const float4*)(h + (size_t)n * HID + tx * 4);
            v.x += hv.x; v.y += hv.y; v.z += hv.z; v.w += hv.w;
        } else {
            int si = (n < C0 + C1) ? 0 : 1;
            int rn = n - C0 - si * C1;
            float4 ew = *(const float4*)(emb_W + ((size_t)si * C1 + rn) * HID + tx * 4);
            float4 eb = *(const float4*)(emb_b + (size_t)si * HID + tx * 4);
            v.x += ew.x + eb.x; v.y += ew.y + eb.y;
            v.z += ew.z + eb.z; v.w += ew.w + eb.w;
        }
        *(float4*)(ht + (size_t)n * HID + tx * 4) = v;
    }
}

// ---------------- fc GEMM: contiguous segment rows, in-place ht ----------------
__global__ __launch_bounds__(256) void fc_gemm(float* __restrict__ ht,
                                               const float* __restrict__ fc_W,
                                               const float* __restrict__ fc_b) {
    __shared__ float As[64][65];
    __shared__ float Bs[64][64];
    const int si = (blockIdx.x < FCT) ? 0 : 1;
    const int t0 = blockIdx.x - si * FCT;
    const int row0 = C0 + si * C1 + t0 * 64;
    const int lim = C0 + (si + 1) * C1;
    const int tid = threadIdx.x;
    for (int i = tid; i < 64 * 16; i += 256) {
        int r = i >> 4, c4 = i & 15;
        int n = row0 + r;
        float4 v = {0.f, 0.f, 0.f, 0.f};
        if (n < lim) v = *(const float4*)(ht + (size_t)n * HID + c4 * 4);
        As[r][c4 * 4 + 0] = v.x; As[r][c4 * 4 + 1] = v.y;
        As[r][c4 * 4 + 2] = v.z; As[r][c4 * 4 + 3] = v.w;
    }
    for (int i = tid; i < 64 * 16; i += 256) {
        int r = i >> 4, c4 = i & 15;
        *(float4*)(&Bs[r][c4 * 4]) = *(const float4*)(fc_W + (size_t)si * HID * HID + (size_t)r * HID + c4 * 4);
    }
    __syncthreads();
    const int tx = tid & 15, ty = tid >> 4;
    float acc[4][4] = {};
    gemm64(As, Bs, acc, tx, ty);
    float4 fb = *(const float4*)(fc_b + (size_t)si * HID + tx * 4);
    #pragma unroll
    for (int rr = 0; rr < 4; ++rr) {
        int n = row0 + ty * 4 + rr;
        if (n >= lim) continue;
        float4 v;
        v.x = acc[rr][0] + fb.x; v.y = acc[rr][1] + fb.y;
        v.z = acc[rr][2] + fb.z; v.w = acc[rr][3] + fb.w;
        *(float4*)(ht + (size_t)n * HID + tx * 4) = v;
    }
}

// ---------------- gnn GEMM + elu + logits ----------------
__global__ __launch_bounds__(256) void gnn_logits(const float* __restrict__ agg,
                                                  const float* __restrict__ gnn_W,
                                                  const float* __restrict__ gnn_b,
                                                  const float* __restrict__ out_W,
                                                  const float* __restrict__ out_b,
                                                  float* __restrict__ out) {
    __shared__ float As[64][65];
    __shared__ float Bs[64][64];
    __shared__ float Wo[64 * NCLS];
    const int row0 = blockIdx.x * 64;
    const int tid = threadIdx.x;
    for (int i = tid; i < 64 * 16; i += 256) {
        int r = i >> 4, c4 = i & 15;
        int n = row0 + r;
        float4 v = {0.f, 0.f, 0.f, 0.f};
        if (n < NN) v = *(const float4*)(agg + (size_t)n * HID + c4 * 4);
        As[r][c4 * 4 + 0] = v.x; As[r][c4 * 4 + 1] = v.y;
        As[r][c4 * 4 + 2] = v.z; As[r][c4 * 4 + 3] = v.w;
    }
    for (int i = tid; i < 64 * 16; i += 256) {
        int r = i >> 4, c4 = i & 15;
        *(float4*)(&Bs[r][c4 * 4]) = *(const float4*)(gnn_W + (size_t)r * HID + c4 * 4);
    }
    if (tid < 256) {
        *(float4*)(&Wo[tid * 4]) = *(const float4*)(out_W + tid * 4);
    }
    __syncthreads();
    const int tx = tid & 15, ty = tid >> 4;
    float acc[4][4] = {};
    gemm64(As, Bs, acc, tx, ty);
    __syncthreads();     // done reading As; reuse it for emb
    float4 gb = *(const float4*)(gnn_b + tx * 4);
    #pragma unroll
    for (int rr = 0; rr < 4; ++rr) {
        int n = row0 + ty * 4 + rr;
        float4 v;
        v.x = acc[rr][0] + gb.x; v.y = acc[rr][1] + gb.y;
        v.z = acc[rr][2] + gb.z; v.w = acc[rr][3] + gb.w;
        v.x = (v.x > 0.f) ? v.x : expm1f(v.x);
        v.y = (v.y > 0.f) ? v.y : expm1f(v.y);
        v.z = (v.z > 0.f) ? v.z : expm1f(v.z);
        v.w = (v.w > 0.f) ? v.w : expm1f(v.w);
        As[ty * 4 + rr][tx * 4 + 0] = v.x; As[ty * 4 + rr][tx * 4 + 1] = v.y;
        As[ty * 4 + rr][tx * 4 + 2] = v.z; As[ty * 4 + rr][tx * 4 + 3] = v.w;
        if (n < NN) *(float4*)(out + (size_t)n * HID + tx * 4) = v;
    }
    __syncthreads();
    // logits: thread -> (row r = tid>>2, classes cq..cq+3)
    const int r = tid >> 2, cq = (tid & 3) * 4;
    float l0 = 0.f, l1 = 0.f, l2 = 0.f, l3 = 0.f;
    #pragma unroll 8
    for (int j = 0; j < 64; ++j) {
        float e = As[r][j];
        float4 w = *(const float4*)(&Wo[j * NCLS + cq]);
        l0 += e * w.x; l1 += e * w.y; l2 += e * w.z; l3 += e * w.w;
    }
    int n = row0 + r;
    if (n < NN) {
        float4 ob = *(const float4*)(out_b + cq);
        float4 lg;
        lg.x = l0 + ob.x; lg.y = l1 + ob.y; lg.z = l2 + ob.z; lg.w = l3 + ob.w;
        const size_t lbase = (size_t)NN * HID;
        *(float4*)(out + lbase + (size_t)n * NCLS + cq) = lg;
        *(float4*)(out + lbase + (size_t)NN * NCLS + (size_t)n * NCLS + cq) = lg;
    }
}

extern "C" void kernel_launch(void* const* d_in, const int* in_sizes, int n_in,
                              void* d_out, int out_size, void* d_ws, size_t ws_size,
                              hipStream_t stream) {
    const float* feats0 = (const float*)d_in[0];
    const float* W_pre  = (const float*)d_in[1];
    const float* b_pre  = (const float*)d_in[2];
    const float* emb_W  = (const float*)d_in[3];
    const float* emb_b  = (const float*)d_in[4];
    const float* op_W   = (const float*)d_in[5];
    const float* op_b   = (const float*)d_in[6];
    const float* fc_W   = (const float*)d_in[7];
    const float* fc_b   = (const float*)d_in[8];
    const float* gnn_W  = (const float*)d_in[9];
    const float* gnn_b  = (const float*)d_in[10];
    const float* out_W  = (const float*)d_in[11];
    const float* out_b  = (const float*)d_in[12];
    const int* src         = (const int*)d_in[13];
    const int* dst         = (const int*)d_in[14];
    const int* node_assign = (const int*)d_in[15];
    float* out = (float*)d_out;

    // workspace layout (~69.2 MB). ebuf aliases agg region (ebuf dead before agg written).
    float* h    = (float*)d_ws;                        // C0*HID
    float* ht   = h + (size_t)C0 * HID;                // NN*HID
    float* agg  = ht + (size_t)NN * HID;               // NN*HID (union w/ ebuf)
    uint2* ebuf = (uint2*)agg;                         // EE uint2 (12.8MB < 25.6MB)
    int* ssrc   = (int*)(agg + (size_t)NN * HID);      // EE
    int* offs   = ssrc + EE;                           // NN+1
    int* split  = offs + NN + 1;                       // NN
    int* perm   = split + NN;                          // NN
    int* nbc    = perm + NN;                           // NBC
    int* gbase  = nbc + NBC;                           // NBC
    int* koff   = gbase + NBC;                         // KK+1
    int* tmap_b = koff + KK + 1;                       // MAXT
    int* tmap_s = tmap_b + MAXT;                       // MAXT
    int* bcnt   = tmap_s + MAXT;                       // NB
    int* bbase  = bcnt + NB;                           // NB
    int* bcur   = bbase + NB;                          // NB

    hipMemsetAsync(bcnt, 0, NB * sizeof(int), stream);

    pre_gemm<<<C0 / 64, 256, 0, stream>>>(feats0, W_pre, b_pre, h);
    bucket_count<<<GR1, 256, 0, stream>>>(dst, bcnt);
    bucket_scan<<<1, 64, 0, stream>>>(bcnt, bbase, bcur, offs);
    coarse_scatter<<<GR1, 256, 0, stream>>>(src, dst, bcur, ebuf);
    fine_scatter<<<NB, 256, 0, stream>>>(ebuf, bbase, bcur, offs, split, ssrc);
    nb_count<<<NB, 256, 0, stream>>>(node_assign, nbc);
    nb_scan<<<1, 256, 0, stream>>>(nbc, gbase, koff, tmap_b, tmap_s);
    nb_scatter<<<NB, 256, 0, stream>>>(node_assign, gbase, perm);
    spmm<<<NN / 16, 256, 0, stream>>>(h, offs, split, ssrc, agg);           // filtered
    op_gemm<<<MAXT, 256, 0, stream>>>(agg, h, perm, koff, tmap_b, tmap_s,
                                      op_W, op_b, emb_W, emb_b, ht);
    fc_gemm<<<2 * FCT, 256, 0, stream>>>(ht, fc_W, fc_b);
    spmm<<<NN / 16, 256, 0, stream>>>(ht, offs, nullptr, ssrc, agg);        // full
    gnn_logits<<<GNT, 256, 0, stream>>>(agg, gnn_W, gnn_b, out_W, out_b, out);
}

// Round 5
// 284.538 us; speedup vs baseline: 2.4187x; 1.0750x over previous
//
#include <hip/hip_runtime.h>
#include <hip/hip_bf16.h>

#define NN   100000
#define C0   40000
#define C1   30000
#define C2   30000
#define HID  64
#define KK   8
#define EE   1600000
#define DIN  512
#define NCLS 16
#define NB   196      // ceil(100000/512) coarse dst buckets
#define BKE  2048     // edges per block in coarse pass
#define GR1  782      // ceil(EE/BKE)
#define NBC  1568     // KK*NB node-bucket counts
#define MAXT 1571     // upper bound on op-GEMM tiles
#define FCT  469      // ceil(30000/64) fc tiles per segment
#define GNT  1563     // ceil(100000/64) gnn tiles

typedef unsigned short ushortT;

__device__ __forceinline__ float b2f(ushortT u) {
    return __uint_as_float((unsigned)u << 16);
}
__device__ __forceinline__ ushortT f2b(float x) {
    unsigned v = __float_as_uint(x);
    unsigned r = (v + 0x7FFF + ((v >> 16) & 1)) >> 16;   // RNE
    return (ushortT)r;
}

// ---------------- pre GEMM: hb[0:40000] = bf16(feats0 @ W_pre + b_pre) ----------------
// M-tile 32 (grid 1250), AsT transposed LDS, conflict-free inner loop.
__global__ __launch_bounds__(256) void pre_gemm(const float* __restrict__ A,
                                                const float* __restrict__ W,
                                                const float* __restrict__ b,
                                                ushortT* __restrict__ hb) {
    __shared__ float AsT[64][34];   // [k][row], pad->34 keeps float2 aligned + conflict-free
    __shared__ float Bs[64][64];
    const int tid = threadIdx.x;
    const int row0 = blockIdx.x * 32;
    const int tx = tid & 15, ty = tid >> 4;   // ty 0..15 -> rows 2ty,2ty+1
    float acc[2][4] = {};
    for (int k0 = 0; k0 < DIN; k0 += 64) {
        // A tile: 32 rows x 64 cols, store transposed
        #pragma unroll
        for (int u = 0; u < 2; ++u) {
            int ii = tid + u * 256;
            int r = ii >> 4, c4 = ii & 15;
            float4 v = *(const float4*)(A + (size_t)(row0 + r) * DIN + k0 + c4 * 4);
            AsT[c4 * 4 + 0][r] = v.x; AsT[c4 * 4 + 1][r] = v.y;
            AsT[c4 * 4 + 2][r] = v.z; AsT[c4 * 4 + 3][r] = v.w;
        }
        // B tile: 64x64
        #pragma unroll
        for (int u = 0; u < 4; ++u) {
            int ii = tid + u * 256;
            int r = ii >> 4, c4 = ii & 15;
            *(float4*)(&Bs[r][c4 * 4]) = *(const float4*)(W + (size_t)(k0 + r) * HID + c4 * 4);
        }
        __syncthreads();
        #pragma unroll 4
        for (int kk = 0; kk < 64; ++kk) {
            float2 av = *(const float2*)(&AsT[kk][ty * 2]);
            float4 bv = *(const float4*)(&Bs[kk][tx * 4]);
            acc[0][0] += av.x * bv.x; acc[0][1] += av.x * bv.y;
            acc[0][2] += av.x * bv.z; acc[0][3] += av.x * bv.w;
            acc[1][0] += av.y * bv.x; acc[1][1] += av.y * bv.y;
            acc[1][2] += av.y * bv.z; acc[1][3] += av.y * bv.w;
        }
        __syncthreads();
    }
    float4 bb = *(const float4*)(b + tx * 4);
    #pragma unroll
    for (int r = 0; r < 2; ++r) {
        int n = row0 + ty * 2 + r;
        ushort4 o;
        o.x = f2b(acc[r][0] + bb.x); o.y = f2b(acc[r][1] + bb.y);
        o.z = f2b(acc[r][2] + bb.z); o.w = f2b(acc[r][3] + bb.w);
        *(ushort4*)(hb + (size_t)n * HID + tx * 4) = o;
    }
}

// ---------------- r0: coarse bucket counts ----------------
__global__ __launch_bounds__(256) void bucket_count(const int* __restrict__ dst,
                                                    int* __restrict__ bcnt) {
    __shared__ int hh[NB];
    for (int i = threadIdx.x; i < NB; i += 256) hh[i] = 0;
    __syncthreads();
    const int base = blockIdx.x * BKE;
    for (int u = 0; u < BKE / 256; ++u) {
        int t = base + threadIdx.x + u * 256;
        if (t < EE) atomicAdd(&hh[dst[t] >> 9], 1);
    }
    __syncthreads();
    for (int i = threadIdx.x; i < NB; i += 256) {
        int c = hh[i];
        if (c) atomicAdd(&bcnt[i], c);
    }
}

__global__ void bucket_scan(const int* __restrict__ bcnt, int* __restrict__ bbase,
                            int* __restrict__ bcur, int* __restrict__ offs) {
    if (threadIdx.x == 0 && blockIdx.x == 0) {
        int run = 0;
        for (int i = 0; i < NB; ++i) { bbase[i] = run; bcur[i] = run; run += bcnt[i]; }
        offs[NN] = EE;
    }
}

// ---------------- r1: coarse scatter ----------------
__global__ __launch_bounds__(256) void coarse_scatter(const int* __restrict__ src,
                                                      const int* __restrict__ dst,
                                                      int* __restrict__ bcur,
                                                      uint2* __restrict__ ebuf) {
    __shared__ int hcnt[NB];
    __shared__ int gbase[NB];
    for (int i = threadIdx.x; i < NB; i += 256) hcnt[i] = 0;
    __syncthreads();
    const int base = blockIdx.x * BKE;
    int mys[8], myd[8], mybin[8], myrank[8];
    #pragma unroll
    for (int u = 0; u < 8; ++u) {
        int t = base + threadIdx.x + u * 256;
        if (t < EE) {
            int d = dst[t];
            mys[u] = src[t]; myd[u] = d; mybin[u] = d >> 9;
            myrank[u] = atomicAdd(&hcnt[mybin[u]], 1);
        } else mybin[u] = -1;
    }
    __syncthreads();
    for (int i = threadIdx.x; i < NB; i += 256) {
        int c = hcnt[i];
        gbase[i] = c ? atomicAdd(&bcur[i], c) : 0;
    }
    __syncthreads();
    #pragma unroll
    for (int u = 0; u < 8; ++u) {
        if (mybin[u] >= 0) {
            uint2 e; e.x = (unsigned)mys[u]; e.y = (unsigned)myd[u];
            ebuf[gbase[mybin[u]] + myrank[u]] = e;
        }
    }
}

// ---------------- r2: per-bucket exact CSR ----------------
__global__ __launch_bounds__(256) void fine_scatter(const uint2* __restrict__ ebuf,
                                                    const int* __restrict__ bbase,
                                                    const int* __restrict__ bend,
                                                    int* __restrict__ offs,
                                                    int* __restrict__ split,
                                                    int* __restrict__ ssrc) {
    __shared__ int hist[1024];
    __shared__ int lofs[1024];
    __shared__ int sm[256];
    const int t = threadIdx.x, b = blockIdx.x;
    const int beg = bbase[b], end = bend[b];
    for (int i = t; i < 1024; i += 256) hist[i] = 0;
    __syncthreads();
    for (int j = beg + t; j < end; j += 256) {
        uint2 e = ebuf[j];
        int bin = ((e.y & 511) << 1) | (e.x < C0 ? 0 : 1);
        atomicAdd(&hist[bin], 1);
    }
    __syncthreads();
    int v0 = hist[4 * t], v1 = hist[4 * t + 1], v2 = hist[4 * t + 2], v3 = hist[4 * t + 3];
    int ts = v0 + v1 + v2 + v3;
    sm[t] = ts;
    __syncthreads();
    for (int off = 1; off < 256; off <<= 1) {
        int y = (t >= off) ? sm[t - off] : 0;
        __syncthreads();
        sm[t] += y;
        __syncthreads();
    }
    int pre = sm[t] - ts;
    lofs[4 * t] = pre; lofs[4 * t + 1] = pre + v0;
    lofs[4 * t + 2] = pre + v0 + v1; lofs[4 * t + 3] = pre + v0 + v1 + v2;
    __syncthreads();
    const int d0 = b * 512;
    for (int i = t; i < 512; i += 256) {
        int n = d0 + i;
        if (n < NN) {
            offs[n]  = beg + lofs[2 * i];
            split[n] = beg + lofs[2 * i + 1];
        }
    }
    __syncthreads();
    for (int j = beg + t; j < end; j += 256) {
        uint2 e = ebuf[j];
        int bin = ((e.y & 511) << 1) | (e.x < C0 ? 0 : 1);
        int pos = beg + atomicAdd(&lofs[bin], 1);
        ssrc[pos] = (int)e.x;
    }
}

// ---------------- node buckets by k ----------------
__global__ __launch_bounds__(256) void nb_count(const int* __restrict__ na,
                                                int* __restrict__ nbc) {
    __shared__ int hist[KK];
    const int t = threadIdx.x, b = blockIdx.x;
    if (t < KK) hist[t] = 0;
    __syncthreads();
    #pragma unroll
    for (int u = 0; u < 2; ++u) {
        int n = b * 512 + t + u * 256;
        if (n < NN) atomicAdd(&hist[na[n]], 1);
    }
    __syncthreads();
    if (t < KK) nbc[t * NB + b] = hist[t];
}

__global__ __launch_bounds__(256) void nb_scan(const int* __restrict__ nbc,
                                               int* __restrict__ gbase,
                                               int* __restrict__ koff,
                                               int* __restrict__ tmap_b,
                                               int* __restrict__ tmap_s) {
    __shared__ int sm[256];
    __shared__ int carry;
    __shared__ int tl[KK];
    const int t = threadIdx.x;
    if (t == 0) carry = 0;
    for (int i = t; i < MAXT; i += 256) tmap_b[i] = -1;
    __syncthreads();
    for (int c = 0; c < 7; ++c) {
        int i = c * 256 + t;
        int v = (i < NBC) ? nbc[i] : 0;
        sm[t] = v;
        __syncthreads();
        for (int off = 1; off < 256; off <<= 1) {
            int y = (t >= off) ? sm[t - off] : 0;
            __syncthreads();
            sm[t] += y;
            __syncthreads();
        }
        int base = carry;
        int excl = base + sm[t] - v;
        if (i < NBC) {
            gbase[i] = excl;
            if ((i % NB) == 0) koff[i / NB] = excl;
        }
        __syncthreads();
        if (t == 255) carry = base + sm[255];
        __syncthreads();
    }
    __syncthreads();
    if (t == 0) {
        koff[KK] = NN;
        int run = 0;
        for (int k = 0; k < KK; ++k) {
            tl[k] = run;
            int cnt = ((k == KK - 1) ? NN : koff[k + 1]) - koff[k];
            run += (cnt + 63) / 64;
        }
    }
    __syncthreads();
    if (t < KK) {
        int k = t;
        int kb = koff[k];
        int ke = (k == KK - 1) ? NN : koff[k + 1];
        int nt = (ke - kb + 63) / 64;
        for (int tt = 0; tt < nt; ++tt) {
            tmap_b[tl[k] + tt] = k;
            tmap_s[tl[k] + tt] = kb + tt * 64;
        }
    }
}

__global__ __launch_bounds__(256) void nb_scatter(const int* __restrict__ na,
                                                  const int* __restrict__ gbase,
                                                  int* __restrict__ perm) {
    __shared__ int hist[KK];
    __shared__ int gb[KK];
    const int t = threadIdx.x, b = blockIdx.x;
    if (t < KK) { hist[t] = 0; gb[t] = gbase[t * NB + b]; }
    __syncthreads();
    #pragma unroll
    for (int u = 0; u < 2; ++u) {
        int n = b * 512 + t + u * 256;
        if (n < NN) {
            int k = na[n];
            int r = atomicAdd(&hist[k], 1);
            perm[gb[k] + r] = n;
        }
    }
}

// ---------------- spmm over bf16 rows: 16-lane group per node ----------------
__global__ __launch_bounds__(256) void spmm(const ushortT* __restrict__ rows,
                                            const int* __restrict__ offs,
                                            const int* __restrict__ splt,
                                            const int* __restrict__ ssrc,
                                            float* __restrict__ agg) {
    const int t = threadIdx.x;
    const int g = t >> 4, c4 = t & 15;
    const int n = blockIdx.x * 16 + g;
    const int beg = offs[n], endf = offs[n + 1];
    const int ge = splt ? splt[n] : endf;
    float4 a0 = {0.f, 0.f, 0.f, 0.f}, a1 = {0.f, 0.f, 0.f, 0.f};
    int j = beg;
    for (; j + 2 <= ge; j += 2) {
        int s0 = ssrc[j], s1 = ssrc[j + 1];
        ushort4 u = *(const ushort4*)(rows + (size_t)s0 * HID + c4 * 4);
        ushort4 v = *(const ushort4*)(rows + (size_t)s1 * HID + c4 * 4);
        a0.x += b2f(u.x); a0.y += b2f(u.y); a0.z += b2f(u.z); a0.w += b2f(u.w);
        a1.x += b2f(v.x); a1.y += b2f(v.y); a1.z += b2f(v.z); a1.w += b2f(v.w);
    }
    if (j < ge) {
        ushort4 u = *(const ushort4*)(rows + (size_t)ssrc[j] * HID + c4 * 4);
        a0.x += b2f(u.x); a0.y += b2f(u.y); a0.z += b2f(u.z); a0.w += b2f(u.w);
    }
    const float inv = 1.0f / fmaxf((float)(endf - beg), 1.0f);
    float4 r;
    r.x = (a0.x + a1.x) * inv; r.y = (a0.y + a1.y) * inv;
    r.z = (a0.z + a1.z) * inv; r.w = (a0.w + a1.w) * inv;
    *(float4*)(agg + (size_t)n * HID + c4 * 4) = r;
}

// ---------------- shared 64x64x64 GEMM core ----------------
__device__ __forceinline__ void gemm64(const float As[64][65], const float Bs[64][64],
                                       float acc[4][4], int tx, int ty) {
    for (int kk = 0; kk < 64; ++kk) {
        float a0 = As[ty * 4 + 0][kk], a1 = As[ty * 4 + 1][kk];
        float a2 = As[ty * 4 + 2][kk], a3 = As[ty * 4 + 3][kk];
        float4 bv = *(const float4*)(&Bs[kk][tx * 4]);
        acc[0][0] += a0 * bv.x; acc[0][1] += a0 * bv.y; acc[0][2] += a0 * bv.z; acc[0][3] += a0 * bv.w;
        acc[1][0] += a1 * bv.x; acc[1][1] += a1 * bv.y; acc[1][2] += a1 * bv.z; acc[1][3] += a1 * bv.w;
        acc[2][0] += a2 * bv.x; acc[2][1] += a2 * bv.y; acc[2][2] += a2 * bv.z; acc[2][3] += a2 * bv.w;
        acc[3][0] += a3 * bv.x; acc[3][1] += a3 * bv.y; acc[3][2] += a3 * bv.z; acc[3][3] += a3 * bv.w;
    }
}

// ---------------- op GEMM: k-bucketed tiles -> htb (bf16) ----------------
__global__ __launch_bounds__(256) void op_gemm(const float* __restrict__ agg,
                                               const ushortT* __restrict__ hb,
                                               const int* __restrict__ perm,
                                               const int* __restrict__ koff,
                                               const int* __restrict__ tmap_b,
                                               const int* __restrict__ tmap_s,
                                               const float* __restrict__ op_W,
                                               const float* __restrict__ op_b,
                                               const float* __restrict__ emb_W,
                                               const float* __restrict__ emb_b,
                                               ushortT* __restrict__ htb) {
    __shared__ float As[64][65];
    __shared__ float Bs[64][64];
    __shared__ int idx[64];
    const int bk = tmap_b[blockIdx.x];
    if (bk < 0) return;
    const int start = tmap_s[blockIdx.x];
    const int kend = koff[bk + 1];
    const int tid = threadIdx.x;
    if (tid < 64) {
        int p = start + tid;
        idx[tid] = (p < kend) ? perm[p] : -1;
    }
    __syncthreads();
    for (int i = tid; i < 64 * 16; i += 256) {
        int r = i >> 4, c4 = i & 15;
        int n = idx[r];
        float4 v = {0.f, 0.f, 0.f, 0.f};
        if (n >= 0) v = *(const float4*)(agg + (size_t)n * HID + c4 * 4);
        As[r][c4 * 4 + 0] = v.x; As[r][c4 * 4 + 1] = v.y;
        As[r][c4 * 4 + 2] = v.z; As[r][c4 * 4 + 3] = v.w;
    }
    for (int i = tid; i < 64 * 16; i += 256) {
        int r = i >> 4, c4 = i & 15;
        *(float4*)(&Bs[r][c4 * 4]) = *(const float4*)(op_W + (size_t)bk * HID * HID + (size_t)r * HID + c4 * 4);
    }
    __syncthreads();
    const int tx = tid & 15, ty = tid >> 4;
    float acc[4][4] = {};
    gemm64(As, Bs, acc, tx, ty);
    float4 ob = *(const float4*)(op_b + (size_t)bk * HID + tx * 4);
    #pragma unroll
    for (int rr = 0; rr < 4; ++rr) {
        int n = idx[ty * 4 + rr];
        if (n < 0) continue;
        float4 v;
        v.x = acc[rr][0] + ob.x; v.y = acc[rr][1] + ob.y;
        v.z = acc[rr][2] + ob.z; v.w = acc[rr][3] + ob.w;
        if (n < C0) {
            ushort4 hu = *(const ushort4*)(hb + (size_t)n * HID + tx * 4);
            v.x += b2f(hu.x); v.y += b2f(hu.y); v.z += b2f(hu.z); v.w += b2f(hu.w);
        } else {
            int si = (n < C0 + C1) ? 0 : 1;
            int rn = n - C0 - si * C1;
            float4 ew = *(const float4*)(emb_W + ((size_t)si * C1 + rn) * HID + tx * 4);
            float4 eb = *(const float4*)(emb_b + (size_t)si * HID + tx * 4);
            v.x += ew.x + eb.x; v.y += ew.y + eb.y;
            v.z += ew.z + eb.z; v.w += ew.w + eb.w;
        }
        ushort4 o;
        o.x = f2b(v.x); o.y = f2b(v.y); o.z = f2b(v.z); o.w = f2b(v.w);
        *(ushort4*)(htb + (size_t)n * HID + tx * 4) = o;
    }
}

// ---------------- fc GEMM: contiguous segment rows, in-place htb ----------------
__global__ __launch_bounds__(256) void fc_gemm(ushortT* __restrict__ htb,
                                               const float* __restrict__ fc_W,
                                               const float* __restrict__ fc_b) {
    __shared__ float As[64][65];
    __shared__ float Bs[64][64];
    const int si = (blockIdx.x < FCT) ? 0 : 1;
    const int t0 = blockIdx.x - si * FCT;
    const int row0 = C0 + si * C1 + t0 * 64;
    const int lim = C0 + (si + 1) * C1;
    const int tid = threadIdx.x;
    for (int i = tid; i < 64 * 16; i += 256) {
        int r = i >> 4, c4 = i & 15;
        int n = row0 + r;
        if (n < lim) {
            ushort4 u = *(const ushort4*)(htb + (size_t)n * HID + c4 * 4);
            As[r][c4 * 4 + 0] = b2f(u.x); As[r][c4 * 4 + 1] = b2f(u.y);
            As[r][c4 * 4 + 2] = b2f(u.z); As[r][c4 * 4 + 3] = b2f(u.w);
        } else {
            As[r][c4 * 4 + 0] = 0.f; As[r][c4 * 4 + 1] = 0.f;
            As[r][c4 * 4 + 2] = 0.f; As[r][c4 * 4 + 3] = 0.f;
        }
    }
    for (int i = tid; i < 64 * 16; i += 256) {
        int r = i >> 4, c4 = i & 15;
        *(float4*)(&Bs[r][c4 * 4]) = *(const float4*)(fc_W + (size_t)si * HID * HID + (size_t)r * HID + c4 * 4);
    }
    __syncthreads();
    const int tx = tid & 15, ty = tid >> 4;
    float acc[4][4] = {};
    gemm64(As, Bs, acc, tx, ty);
    float4 fb = *(const float4*)(fc_b + (size_t)si * HID + tx * 4);
    #pragma unroll
    for (int rr = 0; rr < 4; ++rr) {
        int n = row0 + ty * 4 + rr;
        if (n >= lim) continue;
        ushort4 o;
        o.x = f2b(acc[rr][0] + fb.x); o.y = f2b(acc[rr][1] + fb.y);
        o.z = f2b(acc[rr][2] + fb.z); o.w = f2b(acc[rr][3] + fb.w);
        *(ushort4*)(htb + (size_t)n * HID + tx * 4) = o;
    }
}

// ---------------- gnn GEMM + elu + logits ----------------
__global__ __launch_bounds__(256) void gnn_logits(const float* __restrict__ agg,
                                                  const float* __restrict__ gnn_W,
                                                  const float* __restrict__ gnn_b,
                                                  const float* __restrict__ out_W,
                                                  const float* __restrict__ out_b,
                                                  float* __restrict__ out) {
    __shared__ float As[64][65];
    __shared__ float Bs[64][64];
    __shared__ float Wo[64 * NCLS];
    const int row0 = blockIdx.x * 64;
    const int tid = threadIdx.x;
    for (int i = tid; i < 64 * 16; i += 256) {
        int r = i >> 4, c4 = i & 15;
        int n = row0 + r;
        float4 v = {0.f, 0.f, 0.f, 0.f};
        if (n < NN) v = *(const float4*)(agg + (size_t)n * HID + c4 * 4);
        As[r][c4 * 4 + 0] = v.x; As[r][c4 * 4 + 1] = v.y;
        As[r][c4 * 4 + 2] = v.z; As[r][c4 * 4 + 3] = v.w;
    }
    for (int i = tid; i < 64 * 16; i += 256) {
        int r = i >> 4, c4 = i & 15;
        *(float4*)(&Bs[r][c4 * 4]) = *(const float4*)(gnn_W + (size_t)r * HID + c4 * 4);
    }
    if (tid < 256) {
        *(float4*)(&Wo[tid * 4]) = *(const float4*)(out_W + tid * 4);
    }
    __syncthreads();
    const int tx = tid & 15, ty = tid >> 4;
    float acc[4][4] = {};
    gemm64(As, Bs, acc, tx, ty);
    __syncthreads();
    float4 gb = *(const float4*)(gnn_b + tx * 4);
    #pragma unroll
    for (int rr = 0; rr < 4; ++rr) {
        int n = row0 + ty * 4 + rr;
        float4 v;
        v.x = acc[rr][0] + gb.x; v.y = acc[rr][1] + gb.y;
        v.z = acc[rr][2] + gb.z; v.w = acc[rr][3] + gb.w;
        v.x = (v.x > 0.f) ? v.x : expm1f(v.x);
        v.y = (v.y > 0.f) ? v.y : expm1f(v.y);
        v.z = (v.z > 0.f) ? v.z : expm1f(v.z);
        v.w = (v.w > 0.f) ? v.w : expm1f(v.w);
        As[ty * 4 + rr][tx * 4 + 0] = v.x; As[ty * 4 + rr][tx * 4 + 1] = v.y;
        As[ty * 4 + rr][tx * 4 + 2] = v.z; As[ty * 4 + rr][tx * 4 + 3] = v.w;
        if (n < NN) *(float4*)(out + (size_t)n * HID + tx * 4) = v;
    }
    __syncthreads();
    const int r = tid >> 2, cq = (tid & 3) * 4;
    float l0 = 0.f, l1 = 0.f, l2 = 0.f, l3 = 0.f;
    #pragma unroll 8
    for (int j = 0; j < 64; ++j) {
        float e = As[r][j];
        float4 w = *(const float4*)(&Wo[j * NCLS + cq]);
        l0 += e * w.x; l1 += e * w.y; l2 += e * w.z; l3 += e * w.w;
    }
    int n = row0 + r;
    if (n < NN) {
        float4 ob = *(const float4*)(out_b + cq);
        float4 lg;
        lg.x = l0 + ob.x; lg.y = l1 + ob.y; lg.z = l2 + ob.z; lg.w = l3 + ob.w;
        const size_t lbase = (size_t)NN * HID;
        *(float4*)(out + lbase + (size_t)n * NCLS + cq) = lg;
        *(float4*)(out + lbase + (size_t)NN * NCLS + (size_t)n * NCLS + cq) = lg;
    }
}

extern "C" void kernel_launch(void* const* d_in, const int* in_sizes, int n_in,
                              void* d_out, int out_size, void* d_ws, size_t ws_size,
                              hipStream_t stream) {
    const float* feats0 = (const float*)d_in[0];
    const float* W_pre  = (const float*)d_in[1];
    const float* b_pre  = (const float*)d_in[2];
    const float* emb_W  = (const float*)d_in[3];
    const float* emb_b  = (const float*)d_in[4];
    const float* op_W   = (const float*)d_in[5];
    const float* op_b   = (const float*)d_in[6];
    const float* fc_W   = (const float*)d_in[7];
    const float* fc_b   = (const float*)d_in[8];
    const float* gnn_W  = (const float*)d_in[9];
    const float* gnn_b  = (const float*)d_in[10];
    const float* out_W  = (const float*)d_in[11];
    const float* out_b  = (const float*)d_in[12];
    const int* src         = (const int*)d_in[13];
    const int* dst         = (const int*)d_in[14];
    const int* node_assign = (const int*)d_in[15];
    float* out = (float*)d_out;

    // workspace layout (~51 MB). ebuf aliases agg (ebuf dead before agg written).
    ushortT* hb  = (ushortT*)d_ws;                     // C0*HID bf16 (5.12 MB)
    ushortT* htb = hb + (size_t)C0 * HID;              // NN*HID bf16 (12.8 MB)
    float* agg  = (float*)(htb + (size_t)NN * HID);    // NN*HID f32 (25.6 MB)
    uint2* ebuf = (uint2*)agg;                         // EE uint2 (12.8 MB)
    int* ssrc   = (int*)(agg + (size_t)NN * HID);      // EE
    int* offs   = ssrc + EE;                           // NN+1
    int* split  = offs + NN + 1;                       // NN
    int* perm   = split + NN;                          // NN
    int* nbc    = perm + NN;                           // NBC
    int* gbase  = nbc + NBC;                           // NBC
    int* koff   = gbase + NBC;                         // KK+1
    int* tmap_b = koff + KK + 1;                       // MAXT
    int* tmap_s = tmap_b + MAXT;                       // MAXT
    int* bcnt   = tmap_s + MAXT;                       // NB
    int* bbase  = bcnt + NB;                           // NB
    int* bcur   = bbase + NB;                          // NB

    hipMemsetAsync(bcnt, 0, NB * sizeof(int), stream);

    pre_gemm<<<C0 / 32, 256, 0, stream>>>(feats0, W_pre, b_pre, hb);
    bucket_count<<<GR1, 256, 0, stream>>>(dst, bcnt);
    bucket_scan<<<1, 64, 0, stream>>>(bcnt, bbase, bcur, offs);
    coarse_scatter<<<GR1, 256, 0, stream>>>(src, dst, bcur, ebuf);
    fine_scatter<<<NB, 256, 0, stream>>>(ebuf, bbase, bcur, offs, split, ssrc);
    nb_count<<<NB, 256, 0, stream>>>(node_assign, nbc);
    nb_scan<<<1, 256, 0, stream>>>(nbc, gbase, koff, tmap_b, tmap_s);
    nb_scatter<<<NB, 256, 0, stream>>>(node_assign, gbase, perm);
    spmm<<<NN / 16, 256, 0, stream>>>(hb, offs, split, ssrc, agg);          // filtered
    op_gemm<<<MAXT, 256, 0, stream>>>(agg, hb, perm, koff, tmap_b, tmap_s,
                                      op_W, op_b, emb_W, emb_b, htb);
    fc_gemm<<<2 * FCT, 256, 0, stream>>>(htb, fc_W, fc_b);
    spmm<<<NN / 16, 256, 0, stream>>>(htb, offs, nullptr, ssrc, agg);       // full
    gnn_logits<<<GNT, 256, 0, stream>>>(agg, gnn_W, gnn_b, out_W, out_b, out);
}

// Round 6
// 254.099 us; speedup vs baseline: 2.7084x; 1.1198x over previous
//
#include <hip/hip_runtime.h>
#include <hip/hip_bf16.h>

#define NN   100000
#define C0   40000
#define C1   30000
#define C2   30000
#define HID  64
#define KK   8
#define EE   1600000
#define DIN  512
#define NCLS 16
#define NB   196      // ceil(100000/512) coarse dst buckets
#define BKE  2048     // edges per block in coarse pass
#define GR1  782      // ceil(EE/BKE)
#define NBC  1568     // KK*NB node-bucket counts
#define MAXT 1571     // upper bound on op-GEMM tiles
#define FCT  469      // ceil(30000/64) fc tiles per segment
#define GNT  1563     // ceil(100000/64) gnn tiles
#define AP   88       // LDS row pitch (bf16 units): 176B -> 2-way conflicts, 16B aligned

typedef unsigned short ushortT;
typedef __attribute__((ext_vector_type(8))) short bf16x8;
typedef __attribute__((ext_vector_type(4))) float f32x4;

__device__ __forceinline__ float b2f(ushortT u) {
    return __uint_as_float((unsigned)u << 16);
}
__device__ __forceinline__ ushortT f2b(float x) {
    unsigned v = __float_as_uint(x);
    unsigned r = (v + 0x7FFF + ((v >> 16) & 1)) >> 16;   // RNE
    return (ushortT)r;
}
__device__ __forceinline__ unsigned pk2(float lo, float hi) {
    return (unsigned)f2b(lo) | ((unsigned)f2b(hi) << 16);
}

// ---------------- W_pre -> bf16 transposed [64 cols][512 k] ----------------
__global__ __launch_bounds__(256) void wt_conv(const float* __restrict__ W,
                                               ushortT* __restrict__ WT) {
    int idx = blockIdx.x * 256 + threadIdx.x;   // 0..4095
    int c = idx >> 6, k8 = (idx & 63) * 8;
    uint4 v;
    v.x = pk2(W[(size_t)(k8 + 0) * HID + c], W[(size_t)(k8 + 1) * HID + c]);
    v.y = pk2(W[(size_t)(k8 + 2) * HID + c], W[(size_t)(k8 + 3) * HID + c]);
    v.z = pk2(W[(size_t)(k8 + 4) * HID + c], W[(size_t)(k8 + 5) * HID + c]);
    v.w = pk2(W[(size_t)(k8 + 6) * HID + c], W[(size_t)(k8 + 7) * HID + c]);
    *(uint4*)(WT + (size_t)c * DIN + k8) = v;
}

// ---------------- pre GEMM via MFMA: hb = bf16(feats0 @ W_pre + b_pre) ----------------
// 64 rows/block, 4 waves x (16 rows x 64 cols), K-tiles of 64, double-buffered LDS.
__global__ __launch_bounds__(256) void pre_mfma(const float* __restrict__ A,
                                                const ushortT* __restrict__ WT,
                                                const float* __restrict__ b,
                                                ushortT* __restrict__ hb) {
    __shared__ ushortT Ak[2][64 * AP];
    __shared__ ushortT Bk[2][64 * AP];
    const int tid = threadIdx.x;
    const int row0 = blockIdx.x * 64;
    const int rr = tid >> 2, q = tid & 3;          // staging coords
    const int w = tid >> 6, l = tid & 63;
    const int lr = l & 15, g = l >> 4;             // fragment coords
    f32x4 acc[4] = {{0.f,0.f,0.f,0.f},{0.f,0.f,0.f,0.f},{0.f,0.f,0.f,0.f},{0.f,0.f,0.f,0.f}};
    float4 av0, av1, av2, av3;
    uint4 bv0, bv1;
    // stage tile 0 into regs
    {
        const float* ap = A + (size_t)(row0 + rr) * DIN + q * 16;
        av0 = *(const float4*)(ap + 0);  av1 = *(const float4*)(ap + 4);
        av2 = *(const float4*)(ap + 8);  av3 = *(const float4*)(ap + 12);
        const uint4* bp = (const uint4*)(WT + (size_t)rr * DIN + q * 16);
        bv0 = bp[0]; bv1 = bp[1];
    }
    // write buf 0
    {
        uint4 ua0, ua1;
        ua0.x = pk2(av0.x, av0.y); ua0.y = pk2(av0.z, av0.w);
        ua0.z = pk2(av1.x, av1.y); ua0.w = pk2(av1.z, av1.w);
        ua1.x = pk2(av2.x, av2.y); ua1.y = pk2(av2.z, av2.w);
        ua1.z = pk2(av3.x, av3.y); ua1.w = pk2(av3.z, av3.w);
        *(uint4*)&Ak[0][rr * AP + q * 16] = ua0;
        *(uint4*)&Ak[0][rr * AP + q * 16 + 8] = ua1;
        *(uint4*)&Bk[0][rr * AP + q * 16] = bv0;
        *(uint4*)&Bk[0][rr * AP + q * 16 + 8] = bv1;
    }
    __syncthreads();
    for (int t = 0; t < 8; ++t) {
        if (t < 7) {
            const int k0 = (t + 1) * 64;
            const float* ap = A + (size_t)(row0 + rr) * DIN + k0 + q * 16;
            av0 = *(const float4*)(ap + 0);  av1 = *(const float4*)(ap + 4);
            av2 = *(const float4*)(ap + 8);  av3 = *(const float4*)(ap + 12);
            const uint4* bp = (const uint4*)(WT + (size_t)rr * DIN + k0 + q * 16);
            bv0 = bp[0]; bv1 = bp[1];
        }
        const int bu = t & 1;
        #pragma unroll
        for (int s = 0; s < 2; ++s) {
            bf16x8 af = *(const bf16x8*)&Ak[bu][(w * 16 + lr) * AP + s * 32 + g * 8];
            #pragma unroll
            for (int n = 0; n < 4; ++n) {
                bf16x8 bf = *(const bf16x8*)&Bk[bu][(n * 16 + lr) * AP + s * 32 + g * 8];
                acc[n] = __builtin_amdgcn_mfma_f32_16x16x32_bf16(af, bf, acc[n], 0, 0, 0);
            }
        }
        if (t < 7) {
            const int nb = (t + 1) & 1;
            uint4 ua0, ua1;
            ua0.x = pk2(av0.x, av0.y); ua0.y = pk2(av0.z, av0.w);
            ua0.z = pk2(av1.x, av1.y); ua0.w = pk2(av1.z, av1.w);
            ua1.x = pk2(av2.x, av2.y); ua1.y = pk2(av2.z, av2.w);
            ua1.z = pk2(av3.x, av3.y); ua1.w = pk2(av3.z, av3.w);
            *(uint4*)&Ak[nb][rr * AP + q * 16] = ua0;
            *(uint4*)&Ak[nb][rr * AP + q * 16 + 8] = ua1;
            *(uint4*)&Bk[nb][rr * AP + q * 16] = bv0;
            *(uint4*)&Bk[nb][rr * AP + q * 16 + 8] = bv1;
        }
        __syncthreads();
    }
    // epilogue: D frag row=(g*4+i), col=lr (per n-frag)
    #pragma unroll
    for (int n = 0; n < 4; ++n) {
        float bb = b[n * 16 + lr];
        #pragma unroll
        for (int i = 0; i < 4; ++i) {
            int row = row0 + w * 16 + g * 4 + i;
            hb[(size_t)row * HID + n * 16 + lr] = f2b(acc[n][i] + bb);
        }
    }
}

// ---------------- r0: coarse bucket counts ----------------
__global__ __launch_bounds__(256) void bucket_count(const int* __restrict__ dst,
                                                    int* __restrict__ bcnt) {
    __shared__ int hh[NB];
    for (int i = threadIdx.x; i < NB; i += 256) hh[i] = 0;
    __syncthreads();
    const int base = blockIdx.x * BKE;
    for (int u = 0; u < BKE / 256; ++u) {
        int t = base + threadIdx.x + u * 256;
        if (t < EE) atomicAdd(&hh[dst[t] >> 9], 1);
    }
    __syncthreads();
    for (int i = threadIdx.x; i < NB; i += 256) {
        int c = hh[i];
        if (c) atomicAdd(&bcnt[i], c);
    }
}

__global__ void bucket_scan(const int* __restrict__ bcnt, int* __restrict__ bbase,
                            int* __restrict__ bcur, int* __restrict__ offs) {
    if (threadIdx.x == 0 && blockIdx.x == 0) {
        int run = 0;
        for (int i = 0; i < NB; ++i) { bbase[i] = run; bcur[i] = run; run += bcnt[i]; }
        offs[NN] = EE;
    }
}

// ---------------- r1: coarse scatter ----------------
__global__ __launch_bounds__(256) void coarse_scatter(const int* __restrict__ src,
                                                      const int* __restrict__ dst,
                                                      int* __restrict__ bcur,
                                                      uint2* __restrict__ ebuf) {
    __shared__ int hcnt[NB];
    __shared__ int gbase[NB];
    for (int i = threadIdx.x; i < NB; i += 256) hcnt[i] = 0;
    __syncthreads();
    const int base = blockIdx.x * BKE;
    int mys[8], myd[8], mybin[8], myrank[8];
    #pragma unroll
    for (int u = 0; u < 8; ++u) {
        int t = base + threadIdx.x + u * 256;
        if (t < EE) {
            int d = dst[t];
            mys[u] = src[t]; myd[u] = d; mybin[u] = d >> 9;
            myrank[u] = atomicAdd(&hcnt[mybin[u]], 1);
        } else mybin[u] = -1;
    }
    __syncthreads();
    for (int i = threadIdx.x; i < NB; i += 256) {
        int c = hcnt[i];
        gbase[i] = c ? atomicAdd(&bcur[i], c) : 0;
    }
    __syncthreads();
    #pragma unroll
    for (int u = 0; u < 8; ++u) {
        if (mybin[u] >= 0) {
            uint2 e; e.x = (unsigned)mys[u]; e.y = (unsigned)myd[u];
            ebuf[gbase[mybin[u]] + myrank[u]] = e;
        }
    }
}

// ---------------- r2: per-bucket exact CSR ----------------
__global__ __launch_bounds__(256) void fine_scatter(const uint2* __restrict__ ebuf,
                                                    const int* __restrict__ bbase,
                                                    const int* __restrict__ bend,
                                                    int* __restrict__ offs,
                                                    int* __restrict__ split,
                                                    int* __restrict__ ssrc) {
    __shared__ int hist[1024];
    __shared__ int lofs[1024];
    __shared__ int sm[256];
    const int t = threadIdx.x, b = blockIdx.x;
    const int beg = bbase[b], end = bend[b];
    for (int i = t; i < 1024; i += 256) hist[i] = 0;
    __syncthreads();
    for (int j = beg + t; j < end; j += 256) {
        uint2 e = ebuf[j];
        int bin = ((e.y & 511) << 1) | (e.x < C0 ? 0 : 1);
        atomicAdd(&hist[bin], 1);
    }
    __syncthreads();
    int v0 = hist[4 * t], v1 = hist[4 * t + 1], v2 = hist[4 * t + 2], v3 = hist[4 * t + 3];
    int ts = v0 + v1 + v2 + v3;
    sm[t] = ts;
    __syncthreads();
    for (int off = 1; off < 256; off <<= 1) {
        int y = (t >= off) ? sm[t - off] : 0;
        __syncthreads();
        sm[t] += y;
        __syncthreads();
    }
    int pre = sm[t] - ts;
    lofs[4 * t] = pre; lofs[4 * t + 1] = pre + v0;
    lofs[4 * t + 2] = pre + v0 + v1; lofs[4 * t + 3] = pre + v0 + v1 + v2;
    __syncthreads();
    const int d0 = b * 512;
    for (int i = t; i < 512; i += 256) {
        int n = d0 + i;
        if (n < NN) {
            offs[n]  = beg + lofs[2 * i];
            split[n] = beg + lofs[2 * i + 1];
        }
    }
    __syncthreads();
    for (int j = beg + t; j < end; j += 256) {
        uint2 e = ebuf[j];
        int bin = ((e.y & 511) << 1) | (e.x < C0 ? 0 : 1);
        int pos = beg + atomicAdd(&lofs[bin], 1);
        ssrc[pos] = (int)e.x;
    }
}

// ---------------- node buckets by k ----------------
__global__ __launch_bounds__(256) void nb_count(const int* __restrict__ na,
                                                int* __restrict__ nbc) {
    __shared__ int hist[KK];
    const int t = threadIdx.x, b = blockIdx.x;
    if (t < KK) hist[t] = 0;
    __syncthreads();
    #pragma unroll
    for (int u = 0; u < 2; ++u) {
        int n = b * 512 + t + u * 256;
        if (n < NN) atomicAdd(&hist[na[n]], 1);
    }
    __syncthreads();
    if (t < KK) nbc[t * NB + b] = hist[t];
}

__global__ __launch_bounds__(256) void nb_scan(const int* __restrict__ nbc,
                                               int* __restrict__ gbase,
                                               int* __restrict__ koff,
                                               int* __restrict__ tmap_b,
                                               int* __restrict__ tmap_s) {
    __shared__ int sm[256];
    __shared__ int carry;
    __shared__ int tl[KK];
    const int t = threadIdx.x;
    if (t == 0) carry = 0;
    for (int i = t; i < MAXT; i += 256) tmap_b[i] = -1;
    __syncthreads();
    for (int c = 0; c < 7; ++c) {
        int i = c * 256 + t;
        int v = (i < NBC) ? nbc[i] : 0;
        sm[t] = v;
        __syncthreads();
        for (int off = 1; off < 256; off <<= 1) {
            int y = (t >= off) ? sm[t - off] : 0;
            __syncthreads();
            sm[t] += y;
            __syncthreads();
        }
        int base = carry;
        int excl = base + sm[t] - v;
        if (i < NBC) {
            gbase[i] = excl;
            if ((i % NB) == 0) koff[i / NB] = excl;
        }
        __syncthreads();
        if (t == 255) carry = base + sm[255];
        __syncthreads();
    }
    __syncthreads();
    if (t == 0) {
        koff[KK] = NN;
        int run = 0;
        for (int k = 0; k < KK; ++k) {
            tl[k] = run;
            int cnt = ((k == KK - 1) ? NN : koff[k + 1]) - koff[k];
            run += (cnt + 63) / 64;
        }
    }
    __syncthreads();
    if (t < KK) {
        int k = t;
        int kb = koff[k];
        int ke = (k == KK - 1) ? NN : koff[k + 1];
        int nt = (ke - kb + 63) / 64;
        for (int tt = 0; tt < nt; ++tt) {
            tmap_b[tl[k] + tt] = k;
            tmap_s[tl[k] + tt] = kb + tt * 64;
        }
    }
}

__global__ __launch_bounds__(256) void nb_scatter(const int* __restrict__ na,
                                                  const int* __restrict__ gbase,
                                                  int* __restrict__ perm) {
    __shared__ int hist[KK];
    __shared__ int gb[KK];
    const int t = threadIdx.x, b = blockIdx.x;
    if (t < KK) { hist[t] = 0; gb[t] = gbase[t * NB + b]; }
    __syncthreads();
    #pragma unroll
    for (int u = 0; u < 2; ++u) {
        int n = b * 512 + t + u * 256;
        if (n < NN) {
            int k = na[n];
            int r = atomicAdd(&hist[k], 1);
            perm[gb[k] + r] = n;
        }
    }
}

// ---------------- spmm over bf16 rows: 16-lane group per node ----------------
__global__ __launch_bounds__(256) void spmm(const ushortT* __restrict__ rows,
                                            const int* __restrict__ offs,
                                            const int* __restrict__ splt,
                                            const int* __restrict__ ssrc,
                                            float* __restrict__ agg) {
    const int t = threadIdx.x;
    const int g = t >> 4, c4 = t & 15;
    const int n = blockIdx.x * 16 + g;
    const int beg = offs[n], endf = offs[n + 1];
    const int ge = splt ? splt[n] : endf;
    float4 a0 = {0.f, 0.f, 0.f, 0.f}, a1 = {0.f, 0.f, 0.f, 0.f};
    int j = beg;
    for (; j + 2 <= ge; j += 2) {
        int s0 = ssrc[j], s1 = ssrc[j + 1];
        ushort4 u = *(const ushort4*)(rows + (size_t)s0 * HID + c4 * 4);
        ushort4 v = *(const ushort4*)(rows + (size_t)s1 * HID + c4 * 4);
        a0.x += b2f(u.x); a0.y += b2f(u.y); a0.z += b2f(u.z); a0.w += b2f(u.w);
        a1.x += b2f(v.x); a1.y += b2f(v.y); a1.z += b2f(v.z); a1.w += b2f(v.w);
    }
    if (j < ge) {
        ushort4 u = *(const ushort4*)(rows + (size_t)ssrc[j] * HID + c4 * 4);
        a0.x += b2f(u.x); a0.y += b2f(u.y); a0.z += b2f(u.z); a0.w += b2f(u.w);
    }
    const float inv = 1.0f / fmaxf((float)(endf - beg), 1.0f);
    float4 r;
    r.x = (a0.x + a1.x) * inv; r.y = (a0.y + a1.y) * inv;
    r.z = (a0.z + a1.z) * inv; r.w = (a0.w + a1.w) * inv;
    *(float4*)(agg + (size_t)n * HID + c4 * 4) = r;
}

// ---------------- shared 64x64x64 GEMM core ----------------
__device__ __forceinline__ void gemm64(const float As[64][65], const float Bs[64][64],
                                       float acc[4][4], int tx, int ty) {
    for (int kk = 0; kk < 64; ++kk) {
        float a0 = As[ty * 4 + 0][kk], a1 = As[ty * 4 + 1][kk];
        float a2 = As[ty * 4 + 2][kk], a3 = As[ty * 4 + 3][kk];
        float4 bv = *(const float4*)(&Bs[kk][tx * 4]);
        acc[0][0] += a0 * bv.x; acc[0][1] += a0 * bv.y; acc[0][2] += a0 * bv.z; acc[0][3] += a0 * bv.w;
        acc[1][0] += a1 * bv.x; acc[1][1] += a1 * bv.y; acc[1][2] += a1 * bv.z; acc[1][3] += a1 * bv.w;
        acc[2][0] += a2 * bv.x; acc[2][1] += a2 * bv.y; acc[2][2] += a2 * bv.z; acc[2][3] += a2 * bv.w;
        acc[3][0] += a3 * bv.x; acc[3][1] += a3 * bv.y; acc[3][2] += a3 * bv.z; acc[3][3] += a3 * bv.w;
    }
}

// ---------------- op GEMM: k-bucketed tiles -> htb (bf16) ----------------
__global__ __launch_bounds__(256) void op_gemm(const float* __restrict__ agg,
                                               const ushortT* __restrict__ hb,
                                               const int* __restrict__ perm,
                                               const int* __restrict__ koff,
                                               const int* __restrict__ tmap_b,
                                               const int* __restrict__ tmap_s,
                                               const float* __restrict__ op_W,
                                               const float* __restrict__ op_b,
                                               const float* __restrict__ emb_W,
                                               const float* __restrict__ emb_b,
                                               ushortT* __restrict__ htb) {
    __shared__ float As[64][65];
    __shared__ float Bs[64][64];
    __shared__ int idx[64];
    const int bk = tmap_b[blockIdx.x];
    if (bk < 0) return;
    const int start = tmap_s[blockIdx.x];
    const int kend = koff[bk + 1];
    const int tid = threadIdx.x;
    if (tid < 64) {
        int p = start + tid;
        idx[tid] = (p < kend) ? perm[p] : -1;
    }
    __syncthreads();
    for (int i = tid; i < 64 * 16; i += 256) {
        int r = i >> 4, c4 = i & 15;
        int n = idx[r];
        float4 v = {0.f, 0.f, 0.f, 0.f};
        if (n >= 0) v = *(const float4*)(agg + (size_t)n * HID + c4 * 4);
        As[r][c4 * 4 + 0] = v.x; As[r][c4 * 4 + 1] = v.y;
        As[r][c4 * 4 + 2] = v.z; As[r][c4 * 4 + 3] = v.w;
    }
    for (int i = tid; i < 64 * 16; i += 256) {
        int r = i >> 4, c4 = i & 15;
        *(float4*)(&Bs[r][c4 * 4]) = *(const float4*)(op_W + (size_t)bk * HID * HID + (size_t)r * HID + c4 * 4);
    }
    __syncthreads();
    const int tx = tid & 15, ty = tid >> 4;
    float acc[4][4] = {};
    gemm64(As, Bs, acc, tx, ty);
    float4 ob = *(const float4*)(op_b + (size_t)bk * HID + tx * 4);
    #pragma unroll
    for (int rr = 0; rr < 4; ++rr) {
        int n = idx[ty * 4 + rr];
        if (n < 0) continue;
        float4 v;
        v.x = acc[rr][0] + ob.x; v.y = acc[rr][1] + ob.y;
        v.z = acc[rr][2] + ob.z; v.w = acc[rr][3] + ob.w;
        if (n < C0) {
            ushort4 hu = *(const ushort4*)(hb + (size_t)n * HID + tx * 4);
            v.x += b2f(hu.x); v.y += b2f(hu.y); v.z += b2f(hu.z); v.w += b2f(hu.w);
        } else {
            int si = (n < C0 + C1) ? 0 : 1;
            int rn = n - C0 - si * C1;
            float4 ew = *(const float4*)(emb_W + ((size_t)si * C1 + rn) * HID + tx * 4);
            float4 eb = *(const float4*)(emb_b + (size_t)si * HID + tx * 4);
            v.x += ew.x + eb.x; v.y += ew.y + eb.y;
            v.z += ew.z + eb.z; v.w += ew.w + eb.w;
        }
        ushort4 o;
        o.x = f2b(v.x); o.y = f2b(v.y); o.z = f2b(v.z); o.w = f2b(v.w);
        *(ushort4*)(htb + (size_t)n * HID + tx * 4) = o;
    }
}

// ---------------- fc GEMM: contiguous segment rows, in-place htb ----------------
__global__ __launch_bounds__(256) void fc_gemm(ushortT* __restrict__ htb,
                                               const float* __restrict__ fc_W,
                                               const float* __restrict__ fc_b) {
    __shared__ float As[64][65];
    __shared__ float Bs[64][64];
    const int si = (blockIdx.x < FCT) ? 0 : 1;
    const int t0 = blockIdx.x - si * FCT;
    const int row0 = C0 + si * C1 + t0 * 64;
    const int lim = C0 + (si + 1) * C1;
    const int tid = threadIdx.x;
    for (int i = tid; i < 64 * 16; i += 256) {
        int r = i >> 4, c4 = i & 15;
        int n = row0 + r;
        if (n < lim) {
            ushort4 u = *(const ushort4*)(htb + (size_t)n * HID + c4 * 4);
            As[r][c4 * 4 + 0] = b2f(u.x); As[r][c4 * 4 + 1] = b2f(u.y);
            As[r][c4 * 4 + 2] = b2f(u.z); As[r][c4 * 4 + 3] = b2f(u.w);
        } else {
            As[r][c4 * 4 + 0] = 0.f; As[r][c4 * 4 + 1] = 0.f;
            As[r][c4 * 4 + 2] = 0.f; As[r][c4 * 4 + 3] = 0.f;
        }
    }
    for (int i = tid; i < 64 * 16; i += 256) {
        int r = i >> 4, c4 = i & 15;
        *(float4*)(&Bs[r][c4 * 4]) = *(const float4*)(fc_W + (size_t)si * HID * HID + (size_t)r * HID + c4 * 4);
    }
    __syncthreads();
    const int tx = tid & 15, ty = tid >> 4;
    float acc[4][4] = {};
    gemm64(As, Bs, acc, tx, ty);
    float4 fb = *(const float4*)(fc_b + (size_t)si * HID + tx * 4);
    #pragma unroll
    for (int rr = 0; rr < 4; ++rr) {
        int n = row0 + ty * 4 + rr;
        if (n >= lim) continue;
        ushort4 o;
        o.x = f2b(acc[rr][0] + fb.x); o.y = f2b(acc[rr][1] + fb.y);
        o.z = f2b(acc[rr][2] + fb.z); o.w = f2b(acc[rr][3] + fb.w);
        *(ushort4*)(htb + (size_t)n * HID + tx * 4) = o;
    }
}

// ---------------- gnn GEMM + elu + logits ----------------
__global__ __launch_bounds__(256) void gnn_logits(const float* __restrict__ agg,
                                                  const float* __restrict__ gnn_W,
                                                  const float* __restrict__ gnn_b,
                                                  const float* __restrict__ out_W,
                                                  const float* __restrict__ out_b,
                                                  float* __restrict__ out) {
    __shared__ float As[64][65];
    __shared__ float Bs[64][64];
    __shared__ float Wo[64 * NCLS];
    const int row0 = blockIdx.x * 64;
    const int tid = threadIdx.x;
    for (int i = tid; i < 64 * 16; i += 256) {
        int r = i >> 4, c4 = i & 15;
        int n = row0 + r;
        float4 v = {0.f, 0.f, 0.f, 0.f};
        if (n < NN) v = *(const float4*)(agg + (size_t)n * HID + c4 * 4);
        As[r][c4 * 4 + 0] = v.x; As[r][c4 * 4 + 1] = v.y;
        As[r][c4 * 4 + 2] = v.z; As[r][c4 * 4 + 3] = v.w;
    }
    for (int i = tid; i < 64 * 16; i += 256) {
        int r = i >> 4, c4 = i & 15;
        *(float4*)(&Bs[r][c4 * 4]) = *(const float4*)(gnn_W + (size_t)r * HID + c4 * 4);
    }
    if (tid < 256) {
        *(float4*)(&Wo[tid * 4]) = *(const float4*)(out_W + tid * 4);
    }
    __syncthreads();
    const int tx = tid & 15, ty = tid >> 4;
    float acc[4][4] = {};
    gemm64(As, Bs, acc, tx, ty);
    __syncthreads();
    float4 gb = *(const float4*)(gnn_b + tx * 4);
    #pragma unroll
    for (int rr = 0; rr < 4; ++rr) {
        int n = row0 + ty * 4 + rr;
        float4 v;
        v.x = acc[rr][0] + gb.x; v.y = acc[rr][1] + gb.y;
        v.z = acc[rr][2] + gb.z; v.w = acc[rr][3] + gb.w;
        v.x = (v.x > 0.f) ? v.x : expm1f(v.x);
        v.y = (v.y > 0.f) ? v.y : expm1f(v.y);
        v.z = (v.z > 0.f) ? v.z : expm1f(v.z);
        v.w = (v.w > 0.f) ? v.w : expm1f(v.w);
        As[ty * 4 + rr][tx * 4 + 0] = v.x; As[ty * 4 + rr][tx * 4 + 1] = v.y;
        As[ty * 4 + rr][tx * 4 + 2] = v.z; As[ty * 4 + rr][tx * 4 + 3] = v.w;
        if (n < NN) *(float4*)(out + (size_t)n * HID + tx * 4) = v;
    }
    __syncthreads();
    const int r = tid >> 2, cq = (tid & 3) * 4;
    float l0 = 0.f, l1 = 0.f, l2 = 0.f, l3 = 0.f;
    #pragma unroll 8
    for (int j = 0; j < 64; ++j) {
        float e = As[r][j];
        float4 w = *(const float4*)(&Wo[j * NCLS + cq]);
        l0 += e * w.x; l1 += e * w.y; l2 += e * w.z; l3 += e * w.w;
    }
    int n = row0 + r;
    if (n < NN) {
        float4 ob = *(const float4*)(out_b + cq);
        float4 lg;
        lg.x = l0 + ob.x; lg.y = l1 + ob.y; lg.z = l2 + ob.z; lg.w = l3 + ob.w;
        const size_t lbase = (size_t)NN * HID;
        *(float4*)(out + lbase + (size_t)n * NCLS + cq) = lg;
        *(float4*)(out + lbase + (size_t)NN * NCLS + (size_t)n * NCLS + cq) = lg;
    }
}

extern "C" void kernel_launch(void* const* d_in, const int* in_sizes, int n_in,
                              void* d_out, int out_size, void* d_ws, size_t ws_size,
                              hipStream_t stream) {
    const float* feats0 = (const float*)d_in[0];
    const float* W_pre  = (const float*)d_in[1];
    const float* b_pre  = (const float*)d_in[2];
    const float* emb_W  = (const float*)d_in[3];
    const float* emb_b  = (const float*)d_in[4];
    const float* op_W   = (const float*)d_in[5];
    const float* op_b   = (const float*)d_in[6];
    const float* fc_W   = (const float*)d_in[7];
    const float* fc_b   = (const float*)d_in[8];
    const float* gnn_W  = (const float*)d_in[9];
    const float* gnn_b  = (const float*)d_in[10];
    const float* out_W  = (const float*)d_in[11];
    const float* out_b  = (const float*)d_in[12];
    const int* src         = (const int*)d_in[13];
    const int* dst         = (const int*)d_in[14];
    const int* node_assign = (const int*)d_in[15];
    float* out = (float*)d_out;

    // workspace layout (~51 MB). ebuf aliases agg (ebuf dead before agg written).
    ushortT* hb  = (ushortT*)d_ws;                     // C0*HID bf16
    ushortT* htb = hb + (size_t)C0 * HID;              // NN*HID bf16
    float* agg  = (float*)(htb + (size_t)NN * HID);    // NN*HID f32
    uint2* ebuf = (uint2*)agg;                         // EE uint2 (12.8MB < 25.6MB)
    ushortT* WT = (ushortT*)(agg + (size_t)NN * HID);  // 64*512 bf16 (64KB, 16B-aligned)
    int* ssrc   = (int*)(WT + (size_t)HID * DIN);      // EE
    int* offs   = ssrc + EE;                           // NN+1
    int* split  = offs + NN + 1;                       // NN
    int* perm   = split + NN;                          // NN
    int* nbc    = perm + NN;                           // NBC
    int* gbase  = nbc + NBC;                           // NBC
    int* koff   = gbase + NBC;                         // KK+1
    int* tmap_b = koff + KK + 1;                       // MAXT
    int* tmap_s = tmap_b + MAXT;                       // MAXT
    int* bcnt   = tmap_s + MAXT;                       // NB
    int* bbase  = bcnt + NB;                           // NB
    int* bcur   = bbase + NB;                          // NB

    hipMemsetAsync(bcnt, 0, NB * sizeof(int), stream);

    wt_conv<<<16, 256, 0, stream>>>(W_pre, WT);
    pre_mfma<<<C0 / 64, 256, 0, stream>>>(feats0, WT, b_pre, hb);
    bucket_count<<<GR1, 256, 0, stream>>>(dst, bcnt);
    bucket_scan<<<1, 64, 0, stream>>>(bcnt, bbase, bcur, offs);
    coarse_scatter<<<GR1, 256, 0, stream>>>(src, dst, bcur, ebuf);
    fine_scatter<<<NB, 256, 0, stream>>>(ebuf, bbase, bcur, offs, split, ssrc);
    nb_count<<<NB, 256, 0, stream>>>(node_assign, nbc);
    nb_scan<<<1, 256, 0, stream>>>(nbc, gbase, koff, tmap_b, tmap_s);
    nb_scatter<<<NB, 256, 0, stream>>>(node_assign, gbase, perm);
    spmm<<<NN / 16, 256, 0, stream>>>(hb, offs, split, ssrc, agg);          // filtered
    op_gemm<<<MAXT, 256, 0, stream>>>(agg, hb, perm, koff, tmap_b, tmap_s,
                                      op_W, op_b, emb_W, emb_b, htb);
    fc_gemm<<<2 * FCT, 256, 0, stream>>>(htb, fc_W, fc_b);
    spmm<<<NN / 16, 256, 0, stream>>>(htb, offs, nullptr, ssrc, agg);       // full
    gnn_logits<<<GNT, 256, 0, stream>>>(agg, gnn_W, gnn_b, out_W, out_b, out);
}